// Round 2
// 202.506 us; speedup vs baseline: 1.0208x; 1.0208x over previous
//
#include <hip/hip_runtime.h>
#include <math.h>

#define BB 32
#define NN 1024
#define FF 64
#define PP 128
#define KNN 16
#define H2 256  // 2P
#define F2 128  // 2F
#define KSEL 17
#define SVCAP 272

typedef float f32x4 __attribute__((ext_vector_type(4)));
typedef _Float16 f16x8 __attribute__((ext_vector_type(8)));

// ---- transcendental-free gelu: y = x * clamp(0.5 + xc*P(xc^2), 0, 1), xc = clamp(x, +-3.3)
// deg-7 odd collocation fit of Phi(x)-0.5; max |gelu err| ~7e-3, comparable to the
// bf16 rounding noise this revision removes (f16 storage).
#define GC1 0.39616247f
#define GC3 -0.05891477f
#define GC5 0.00563735f
#define GC7 -2.10439e-4f
#define GXC 3.2988f

__device__ __forceinline__ float gelu_poly(float x) {
    float xc = __builtin_amdgcn_fmed3f(x, -GXC, GXC);
    float s = xc * xc;
    float t = fmaf(s, GC7, GC5);
    t = fmaf(s, t, GC3);
    t = fmaf(s, t, GC1);
    float u = fmaf(xc, t, 0.5f);
    u = __builtin_amdgcn_fmed3f(u, 0.0f, 1.0f);
    return x * u;
}

__device__ __forceinline__ f16x8 splat8(float f) {
    _Float16 h = (_Float16)f;
    f16x8 v = {h, h, h, h, h, h, h, h};
    return v;
}

// packed-f16 activation for 8 elements: gelu(g + q); lowers to v_pk_{add,mul,fma,min,max}_f16
// (ffp-contract=fast fuses a*b+c), zero transcendentals.
__device__ __forceinline__ f16x8 act8(f16x8 gv, f16x8 qv) {
    const f16x8 XL = splat8(-GXC), XH = splat8(GXC);
    const f16x8 C1 = splat8(GC1), C3 = splat8(GC3), C5 = splat8(GC5), C7 = splat8(GC7);
    const f16x8 HF = splat8(0.5f), Z = splat8(0.0f), ONE = splat8(1.0f);
    f16x8 x  = gv + qv;
    f16x8 xc = __builtin_elementwise_min(__builtin_elementwise_max(x, XL), XH);
    f16x8 s  = xc * xc;
    f16x8 t  = s * C7 + C5;
    t = s * t + C3;
    t = s * t + C1;
    f16x8 u = xc * t + HF;
    u = __builtin_elementwise_min(__builtin_elementwise_max(u, Z), ONE);
    return x * u;
}

// ------- Kernel A: set-based kNN (blocks 0..4095) + weight-frag prep (4096..4111) ---
__global__ __launch_bounds__(512, 8) void knn_prep(const float* __restrict__ points,
                                                   int* __restrict__ idx_out,
                                                   const float* __restrict__ W1,
                                                   const float* __restrict__ W2,
                                                   _Float16* __restrict__ Wcf,
                                                   _Float16* __restrict__ W2f) {
    if (blockIdx.x >= 4096) {
        // ---- prep path: fragment-swizzled Wcf (gq_gemm B) + W2f (fused B), f16 ----
        int tid = (blockIdx.x - 4096) * 512 + threadIdx.x;   // 0..8191
        if (tid < 4096) {
            const int lane = tid & 63, quad = lane >> 4, l16 = lane & 15;
            const int kk = (tid >> 6) & 1, n_tile = tid >> 7;
            const int n = n_tile * 16 + l16;
            const int kb = kk * 32 + quad * 8;
            f16x8 v;
#pragma unroll
            for (int j = 0; j < 8; ++j) {
                const int k = kb + j;
                float x = (n < 256) ? W1[k * 256 + n]
                                    : (W1[(64 + k) * 256 + (n - 256)] - W1[k * 256 + (n - 256)]);
                v[j] = (_Float16)x;
            }
            *(f16x8*)(Wcf + (size_t)tid * 8) = v;
        } else {
            const int t2 = tid - 4096;
            const int lane = t2 & 63, quad = lane >> 4, l16 = lane & 15;
            const int nt = (t2 >> 6) & 7, kk8 = t2 >> 9;
            const int p = nt * 16 + l16;
            const int hb = kk8 * 32 + quad * 8;
            f16x8 v;
#pragma unroll
            for (int j = 0; j < 8; ++j) v[j] = (_Float16)W2[(size_t)(hb + j) * PP + p];
            *(f16x8*)(W2f + (size_t)t2 * 8) = v;
        }
        return;
    }

    // SoA point storage: stride-4B LDS reads are bank-conflict-free (float4 layout
    // had stride-16B => 8-way conflict on every hot-loop read).
    __shared__ float px[NN], py[NN], pz[NN], rr[NN];
    __shared__ unsigned sv_val[8][SVCAP];
    __shared__ unsigned sv_idx[8][SVCAP];
    __shared__ unsigned tie_idx[8][64];

    const int t = threadIdx.x;
    const int w = t >> 6, lane = t & 63;
    const int b = blockIdx.x >> 7;
    const int q0 = (blockIdx.x & 127) * 8;
    const float* pb = points + (size_t)b * NN * 3;
    const unsigned long long lt = (1ull << lane) - 1ull;

    for (int i = t; i < NN; i += 512) {
        float x = pb[3 * i], y = pb[3 * i + 1], z = pb[3 * i + 2];
        px[i] = x; py[i] = y; pz[i] = z;
        rr[i] = __fadd_rn(__fadd_rn(__fmul_rn(x, x), __fmul_rn(y, y)), __fmul_rn(z, z));
    }
    __syncthreads();

    const int qn = q0 + w;
    const int gq = b * NN + qn;
    const float qx = px[qn], qy = py[qn], qz = pz[qn], qw = rr[qn];

    float D[16];
#pragma unroll
    for (int j = 0; j < 16; ++j) {
        const int m = j * 64 + lane;
        float dot = __fadd_rn(__fadd_rn(__fmul_rn(qx, px[m]), __fmul_rn(qy, py[m])),
                              __fmul_rn(qz, pz[m]));
        D[j] = __fadd_rn(__fadd_rn(__fsub_rn(qw, __fmul_rn(2.0f, dot)), rr[m]), 1e-5f);
    }

    float mnf = D[0];
#pragma unroll
    for (int j = 1; j < 16; ++j) mnf = fminf(mnf, D[j]);
    const unsigned mbits = __float_as_uint(mnf);

    // T_ub via 16-round radix on the HIGH 16 bits of the lane-mins.
    const unsigned mhi = mbits >> 16;
    unsigned Thi = 0;
#pragma unroll
    for (int bit = 15; bit >= 0; --bit) {
        unsigned cand = Thi | (1u << bit);
        int cnt = __popcll(__ballot(mhi < cand));
        if (cnt < KSEL) Thi = cand;
    }
    const unsigned T = (Thi << 16) | 0xFFFFu;

    unsigned base = 0;
#pragma unroll
    for (int j = 0; j < 16; ++j) {
        unsigned vb = __float_as_uint(D[j]);
        bool keep = (vb <= T);
        unsigned long long m = __ballot(keep);
        if (keep) {
            unsigned pos = base + (unsigned)__popcll(m & lt);
            if (pos < SVCAP) { sv_val[w][pos] = vb; sv_idx[w][pos] = j * 64 + lane; }
        }
        base += (unsigned)__popcll(m);
    }
    unsigned C = base > SVCAP ? SVCAP : base;
    const int S = (int)((C + 63) >> 6);

    unsigned Ts = 0;
    if (S == 1) {
        unsigned xv0 = (lane < (int)C) ? sv_val[w][lane] : 0xFFFFFFFFu;
#pragma unroll
        for (int bit = 31; bit >= 0; --bit) {
            unsigned cand = Ts | (1u << bit);
            int cnt = __popcll(__ballot(xv0 < cand));
            if (cnt < KSEL) Ts = cand;
        }
    } else {
        for (int bit = 31; bit >= 0; --bit) {
            unsigned cand = Ts | (1u << bit);
            int cnt = 0;
            for (int s = 0; s < S; ++s) {
                int i = s * 64 + lane;
                unsigned vb = (i < (int)C) ? sv_val[w][i] : 0xFFFFFFFFu;
                cnt += __popcll(__ballot(vb < cand));
            }
            if (cnt < KSEL) Ts = cand;
        }
    }

    int L = 0;
    for (int s = 0; s < S; ++s) {
        int i = s * 64 + lane;
        unsigned vb = (i < (int)C) ? sv_val[w][i] : 0xFFFFFFFFu;
        L += __popcll(__ballot(vb < Ts));
    }
    const int need = KSEL - L;

    unsigned vmin_l = 0xFFFFFFFFu;
    for (int s = 0; s < S; ++s) {
        int i = s * 64 + lane;
        unsigned vb = (i < (int)C) ? sv_val[w][i] : 0xFFFFFFFFu;
        vmin_l = vmin_l < vb ? vmin_l : vb;
    }
#pragma unroll
    for (int off = 32; off >= 1; off >>= 1) {
        unsigned o2 = __shfl_xor(vmin_l, off, 64);
        vmin_l = vmin_l < o2 ? vmin_l : o2;
    }
    const unsigned Vmin = vmin_l;
    unsigned imin_l = 0xFFFFFFFFu;
    for (int s = 0; s < S; ++s) {
        int i = s * 64 + lane;
        unsigned vb = (i < (int)C) ? sv_val[w][i] : 0xFFFFFFFFu;
        unsigned mi = (i < (int)C) ? sv_idx[w][i] : 0xFFFFFFFFu;
        if (vb == Vmin && mi < imin_l) imin_l = mi;
    }
#pragma unroll
    for (int off = 32; off >= 1; off >>= 1) {
        unsigned o2 = __shfl_xor(imin_l, off, 64);
        imin_l = imin_l < o2 ? imin_l : o2;
    }
    const unsigned dropIdx = imin_l;

    int* o = idx_out + (size_t)gq * KNN;
    unsigned wbase = 0, tbase = 0;
    for (int s = 0; s < S; ++s) {
        int i = s * 64 + lane;
        unsigned vb = (i < (int)C) ? sv_val[w][i] : 0xFFFFFFFFu;
        unsigned mi = (i < (int)C) ? sv_idx[w][i] : 0xFFFFFFFFu;
        bool wk = (vb < Ts) && (mi != dropIdx);
        unsigned long long wm = __ballot(wk);
        if (wk) o[wbase + (unsigned)__popcll(wm & lt)] = (int)mi;
        wbase += (unsigned)__popcll(wm);
        bool tk = (vb == Ts);
        unsigned long long tm2 = __ballot(tk);
        if (tk) {
            unsigned tp = tbase + (unsigned)__popcll(tm2 & lt);
            if (tp < 64) tie_idx[w][tp] = mi;
        }
        tbase += (unsigned)__popcll(tm2);
    }
    unsigned tc = tbase > 64 ? 64 : tbase;
    if ((int)tc == need) {
        bool tk = (lane < (int)tc);
        unsigned mi2 = tk ? tie_idx[w][lane] : 0xFFFFFFFFu;
        tk = tk && (mi2 != dropIdx);
        unsigned long long m3 = __ballot(tk);
        if (tk) o[wbase + (unsigned)__popcll(m3 & lt)] = (int)mi2;
    } else if (lane == 0) {
        unsigned pos = wbase;
        for (int r = 0; r < need; ++r) {
            unsigned best = 0xFFFFFFFFu; int bj = 0;
            for (int j2 = 0; j2 < (int)tc; ++j2) {
                unsigned mi = tie_idx[w][j2];
                if (mi < best) { best = mi; bj = j2; }
            }
            tie_idx[w][bj] = 0xFFFFFFFFu;
            if (best != dropIdx) o[pos++] = (int)best;
        }
    }
}

// ---------------- gq_gemm: G = feat@W1a (f16), Q = feat@Wd + b1 (f16) -------------
__global__ __launch_bounds__(256, 4) void gq_gemm(const float* __restrict__ feat,
                                                  const _Float16* __restrict__ Wcf,
                                                  const float* __restrict__ b1,
                                                  _Float16* __restrict__ Gall,
                                                  _Float16* __restrict__ Qall) {
    __shared__ __align__(16) _Float16 st[4][16][136];
    const int t = threadIdx.x, w = t >> 6, lane = t & 63;
    const int quad = lane >> 4, l16 = lane & 15;
    const int m0 = blockIdx.x * 16;

    f16x8 a[2];
#pragma unroll
    for (int kk = 0; kk < 2; ++kk) {
        const float* ap = feat + (size_t)(m0 + l16) * 64 + kk * 32 + quad * 8;
        float4 a0 = *(const float4*)ap, a1 = *(const float4*)(ap + 4);
        f16x8 v;
        v[0] = (_Float16)a0.x; v[1] = (_Float16)a0.y; v[2] = (_Float16)a0.z; v[3] = (_Float16)a0.w;
        v[4] = (_Float16)a1.x; v[5] = (_Float16)a1.y; v[6] = (_Float16)a1.z; v[7] = (_Float16)a1.w;
        a[kk] = v;
    }
    f32x4 acc[8];
#pragma unroll
    for (int nt = 0; nt < 8; ++nt) acc[nt] = (f32x4){0.f, 0.f, 0.f, 0.f};
#pragma unroll
    for (int kk = 0; kk < 2; ++kk)
#pragma unroll
        for (int nt = 0; nt < 8; ++nt) {
            f16x8 bf = *(const f16x8*)(Wcf + (size_t)(((w * 8 + nt) * 2 + kk) * 64 + lane) * 8);
            acc[nt] = __builtin_amdgcn_mfma_f32_16x16x32_f16(a[kk], bf, acc[nt], 0, 0, 0);
        }

    const bool isQ = (w >= 2);
#pragma unroll
    for (int nt = 0; nt < 8; ++nt) {
        const int col = nt * 16 + l16;
        const float bias = isQ ? b1[(w - 2) * 128 + col] : 0.f;
#pragma unroll
        for (int r = 0; r < 4; ++r)
            st[w][quad * 4 + r][col] = (_Float16)(acc[nt][r] + bias);
    }
    __syncthreads();

    const int row = lane >> 2, c = lane & 3;
    const int m = m0 + row;
#pragma unroll
    for (int i = 0; i < 4; ++i) {
        const int col = c * 32 + i * 8;
        f16x8 v = *(const f16x8*)&st[w][row][col];
        if (!isQ) *(f16x8*)(Gall + (size_t)m * H2 + w * 128 + col) = v;
        else      *(f16x8*)(Qall + (size_t)m * H2 + (w - 2) * 128 + col) = v;
    }
}

// ---------------- fused_mlp8: out = mean_k gelu(gelu(G[idx]+Q) @ W2 + b2) -----------
// 256-thr blocks, 2 queries/wave, W2f staged in FOUR 16 KB quarters.
// f16 pipeline: packed v_pk_* activation (zero transcendentals) — the previous
// bf16/f32-exp version was VALU-bound (VALUBusy 63%, MfmaUtil 14%).
__global__ __launch_bounds__(256, 4) void fused_mlp8(const _Float16* __restrict__ Gall,
                                                     const _Float16* __restrict__ Qall,
                                                     const int* __restrict__ knn_idx,
                                                     const _Float16* __restrict__ W2f,
                                                     const float* __restrict__ b2,
                                                     float* __restrict__ out) {
    __shared__ __align__(16) _Float16 w2s[8192];    // 16 KB: one quarter (2 kk8) of W2f
    const int t = threadIdx.x, w = t >> 6, lane = t & 63;
    const int quad = lane >> 4, l16 = lane & 15;

    const int wave_id = blockIdx.x * 4 + w;       // [0, 16384)
    const int q0 = wave_id * 2;                   // queries q0, q0+1
    const int b = q0 >> 10;
    const int nb0 = knn_idx[q0 * KNN + l16];
    const int nb1 = knn_idx[(q0 + 1) * KNN + l16];
    const _Float16* g0 = Gall + ((size_t)(b << 10) + nb0) * H2;
    const _Float16* g1 = Gall + ((size_t)(b << 10) + nb1) * H2;
    const _Float16* qq0 = Qall + (size_t)q0 * H2;
    const _Float16* qq1 = qq0 + H2;

    f32x4 acc[2][8];
#pragma unroll
    for (int tm = 0; tm < 2; ++tm)
#pragma unroll
        for (int nt = 0; nt < 8; ++nt) acc[tm][nt] = (f32x4){0.f, 0.f, 0.f, 0.f};

#pragma unroll
    for (int qtr = 0; qtr < 4; ++qtr) {
        if (qtr) __syncthreads();    // all waves done reading previous quarter
#pragma unroll
        for (int i = 0; i < 4; ++i) {
            f16x8 v = *(const f16x8*)(W2f + (size_t)(qtr * 8192 + i * 2048 + t * 8));
            *(f16x8*)&w2s[i * 2048 + t * 8] = v;
        }
        __syncthreads();

#pragma unroll
        for (int kl = 0; kl < 2; ++kl) {
            const int ho = (qtr * 2 + kl) * 32 + quad * 8;
            f16x8 gA = *(const f16x8*)(g0 + ho);
            f16x8 qA = *(const f16x8*)(qq0 + ho);
            f16x8 gB = *(const f16x8*)(g1 + ho);
            f16x8 qB = *(const f16x8*)(qq1 + ho);
            f16x8 a0 = act8(gA, qA);
            f16x8 a1 = act8(gB, qB);
            const _Float16* bb = &w2s[kl * 4096 + lane * 8];
#pragma unroll
            for (int nt = 0; nt < 8; ++nt) {
                f16x8 bf = *(const f16x8*)(bb + nt * 512);
                acc[0][nt] = __builtin_amdgcn_mfma_f32_16x16x32_f16(a0, bf, acc[0][nt], 0, 0, 0);
                acc[1][nt] = __builtin_amdgcn_mfma_f32_16x16x32_f16(a1, bf, acc[1][nt], 0, 0, 0);
            }
        }
    }

#pragma unroll
    for (int tm = 0; tm < 2; ++tm)
#pragma unroll
        for (int nt = 0; nt < 8; ++nt) {
            const float bias = b2[nt * 16 + l16];
            float s = 0.f;
#pragma unroll
            for (int r = 0; r < 4; ++r) s += gelu_poly(acc[tm][nt][r] + bias);
            s += __shfl_xor(s, 16, 64);
            s += __shfl_xor(s, 32, 64);
            if (quad == 0)
                out[(size_t)(q0 + tm) * PP + nt * 16 + l16] = s * 0.0625f;
        }
}

extern "C" void kernel_launch(void* const* d_in, const int* in_sizes, int n_in,
                              void* d_out, int out_size, void* d_ws, size_t ws_size,
                              hipStream_t stream) {
    const float* points   = (const float*)d_in[0];
    const float* features = (const float*)d_in[1];
    const float* W1 = (const float*)d_in[2];
    const float* b1 = (const float*)d_in[3];
    const float* W2 = (const float*)d_in[4];
    const float* b2 = (const float*)d_in[5];
    float* out = (float*)d_out;

    const size_t IDX_B  = (size_t)BB * NN * KNN * 4;   // 2 MB
    const size_t WCF_B  = 512 * 64 * 2;                // 64 KB
    const size_t W2F_B  = 256 * 128 * 2;               // 64 KB
    const size_t G_B    = (size_t)BB * NN * H2 * 2;    // 16 MB

    int* knn_idx = (int*)d_ws;
    char* p = (char*)d_ws + IDX_B;
    _Float16* Wcf  = (_Float16*)p;  p += WCF_B;
    _Float16* W2f  = (_Float16*)p;  p += W2F_B;
    _Float16* Gall = (_Float16*)p;  p += G_B;
    _Float16* Qall = (_Float16*)p;                     // 16 MB -> total ~34.1 MB

    knn_prep<<<4112, 512, 0, stream>>>(points, knn_idx, W1, W2, Wcf, W2f);
    gq_gemm<<<2048, 256, 0, stream>>>(features, Wcf, b1, Gall, Qall);
    fused_mlp8<<<4096, 256, 0, stream>>>(Gall, Qall, knn_idx, W2f, b2, out);
}

// Round 3
// 200.407 us; speedup vs baseline: 1.0315x; 1.0105x over previous
//
#include <hip/hip_runtime.h>
#include <math.h>

#define BB 32
#define NN 1024
#define FF 64
#define PP 128
#define KNN 16
#define H2 256  // 2P
#define F2 128  // 2F
#define KSEL 17
#define SVCAP 272

typedef float f32x4 __attribute__((ext_vector_type(4)));
typedef _Float16 f16x8 __attribute__((ext_vector_type(8)));

// ---- transcendental-free gelu: y = x * clamp(0.5 + xc*P(xc^2), 0, 1), xc = clamp(x, +-3.3)
#define GC1 0.39616247f
#define GC3 -0.05891477f
#define GC5 0.00563735f
#define GC7 -2.10439e-4f
#define GXC 3.2988f

__device__ __forceinline__ float gelu_poly(float x) {
    float xc = __builtin_amdgcn_fmed3f(x, -GXC, GXC);
    float s = xc * xc;
    float t = fmaf(s, GC7, GC5);
    t = fmaf(s, t, GC3);
    t = fmaf(s, t, GC1);
    float u = fmaf(xc, t, 0.5f);
    u = __builtin_amdgcn_fmed3f(u, 0.0f, 1.0f);
    return x * u;
}

__device__ __forceinline__ f16x8 splat8(float f) {
    _Float16 h = (_Float16)f;
    f16x8 v = {h, h, h, h, h, h, h, h};
    return v;
}

// packed-f16 activation for 8 elements: gelu(g + q); lowers to v_pk_{add,mul,fma,min,max}_f16
__device__ __forceinline__ f16x8 act8(f16x8 gv, f16x8 qv) {
    const f16x8 XL = splat8(-GXC), XH = splat8(GXC);
    const f16x8 C1 = splat8(GC1), C3 = splat8(GC3), C5 = splat8(GC5), C7 = splat8(GC7);
    const f16x8 HF = splat8(0.5f), Z = splat8(0.0f), ONE = splat8(1.0f);
    f16x8 x  = gv + qv;
    f16x8 xc = __builtin_elementwise_min(__builtin_elementwise_max(x, XL), XH);
    f16x8 s  = xc * xc;
    f16x8 t  = s * C7 + C5;
    t = s * t + C3;
    t = s * t + C1;
    f16x8 u = xc * t + HF;
    u = __builtin_elementwise_min(__builtin_elementwise_max(u, Z), ONE);
    return x * u;
}

// ------- Kernel A: set-based kNN (blocks 0..4095) + weight-frag prep (4096..4111) ---
__global__ __launch_bounds__(512, 8) void knn_prep(const float* __restrict__ points,
                                                   int* __restrict__ idx_out,
                                                   const float* __restrict__ W1,
                                                   const float* __restrict__ W2,
                                                   _Float16* __restrict__ Wcf,
                                                   _Float16* __restrict__ W2f) {
    if (blockIdx.x >= 4096) {
        // ---- prep path: fragment-swizzled Wcf (gq_gemm B) + W2f (fused B), f16 ----
        int tid = (blockIdx.x - 4096) * 512 + threadIdx.x;   // 0..8191
        if (tid < 4096) {
            const int lane = tid & 63, quad = lane >> 4, l16 = lane & 15;
            const int kk = (tid >> 6) & 1, n_tile = tid >> 7;
            const int n = n_tile * 16 + l16;
            const int kb = kk * 32 + quad * 8;
            f16x8 v;
#pragma unroll
            for (int j = 0; j < 8; ++j) {
                const int k = kb + j;
                float x = (n < 256) ? W1[k * 256 + n]
                                    : (W1[(64 + k) * 256 + (n - 256)] - W1[k * 256 + (n - 256)]);
                v[j] = (_Float16)x;
            }
            *(f16x8*)(Wcf + (size_t)tid * 8) = v;
        } else {
            const int t2 = tid - 4096;
            const int lane = t2 & 63, quad = lane >> 4, l16 = lane & 15;
            const int nt = (t2 >> 6) & 7, kk8 = t2 >> 9;
            const int p = nt * 16 + l16;
            const int hb = kk8 * 32 + quad * 8;
            f16x8 v;
#pragma unroll
            for (int j = 0; j < 8; ++j) v[j] = (_Float16)W2[(size_t)(hb + j) * PP + p];
            *(f16x8*)(W2f + (size_t)t2 * 8) = v;
        }
        return;
    }

    // SoA point storage: stride-4B LDS reads are bank-conflict-free.
    __shared__ float px[NN], py[NN], pz[NN], rr[NN];
    __shared__ unsigned sv_val[8][SVCAP];
    __shared__ unsigned sv_idx[8][SVCAP];
    __shared__ unsigned tie_idx[8][64];

    const int t = threadIdx.x;
    const int w = t >> 6, lane = t & 63;
    const int b = blockIdx.x >> 7;
    const int q0 = (blockIdx.x & 127) * 8;
    const float* pb = points + (size_t)b * NN * 3;
    const unsigned long long lt = (1ull << lane) - 1ull;

    for (int i = t; i < NN; i += 512) {
        float x = pb[3 * i], y = pb[3 * i + 1], z = pb[3 * i + 2];
        px[i] = x; py[i] = y; pz[i] = z;
        rr[i] = __fadd_rn(__fadd_rn(__fmul_rn(x, x), __fmul_rn(y, y)), __fmul_rn(z, z));
    }
    __syncthreads();

    const int qn = q0 + w;
    const int gq = b * NN + qn;
    const float qx = px[qn], qy = py[qn], qz = pz[qn], qw = rr[qn];

    float D[16];
#pragma unroll
    for (int j = 0; j < 16; ++j) {
        const int m = j * 64 + lane;
        float dot = __fadd_rn(__fadd_rn(__fmul_rn(qx, px[m]), __fmul_rn(qy, py[m])),
                              __fmul_rn(qz, pz[m]));
        D[j] = __fadd_rn(__fadd_rn(__fsub_rn(qw, __fmul_rn(2.0f, dot)), rr[m]), 1e-5f);
    }

    float mnf = D[0];
#pragma unroll
    for (int j = 1; j < 16; ++j) mnf = fminf(mnf, D[j]);
    const unsigned mbits = __float_as_uint(mnf);

    // T_ub via 16-round radix on the HIGH 16 bits of the lane-mins.
    const unsigned mhi = mbits >> 16;
    unsigned Thi = 0;
#pragma unroll
    for (int bit = 15; bit >= 0; --bit) {
        unsigned cand = Thi | (1u << bit);
        int cnt = __popcll(__ballot(mhi < cand));
        if (cnt < KSEL) Thi = cand;
    }
    const unsigned T = (Thi << 16) | 0xFFFFu;

    unsigned base = 0;
#pragma unroll
    for (int j = 0; j < 16; ++j) {
        unsigned vb = __float_as_uint(D[j]);
        bool keep = (vb <= T);
        unsigned long long m = __ballot(keep);
        if (keep) {
            unsigned pos = base + (unsigned)__popcll(m & lt);
            if (pos < SVCAP) { sv_val[w][pos] = vb; sv_idx[w][pos] = j * 64 + lane; }
        }
        base += (unsigned)__popcll(m);
    }
    unsigned C = base > SVCAP ? SVCAP : base;
    const int S = (int)((C + 63) >> 6);

    unsigned Ts = 0;
    if (S == 1) {
        unsigned xv0 = (lane < (int)C) ? sv_val[w][lane] : 0xFFFFFFFFu;
#pragma unroll
        for (int bit = 31; bit >= 0; --bit) {
            unsigned cand = Ts | (1u << bit);
            int cnt = __popcll(__ballot(xv0 < cand));
            if (cnt < KSEL) Ts = cand;
        }
    } else {
        for (int bit = 31; bit >= 0; --bit) {
            unsigned cand = Ts | (1u << bit);
            int cnt = 0;
            for (int s = 0; s < S; ++s) {
                int i = s * 64 + lane;
                unsigned vb = (i < (int)C) ? sv_val[w][i] : 0xFFFFFFFFu;
                cnt += __popcll(__ballot(vb < cand));
            }
            if (cnt < KSEL) Ts = cand;
        }
    }

    int L = 0;
    for (int s = 0; s < S; ++s) {
        int i = s * 64 + lane;
        unsigned vb = (i < (int)C) ? sv_val[w][i] : 0xFFFFFFFFu;
        L += __popcll(__ballot(vb < Ts));
    }
    const int need = KSEL - L;

    unsigned vmin_l = 0xFFFFFFFFu;
    for (int s = 0; s < S; ++s) {
        int i = s * 64 + lane;
        unsigned vb = (i < (int)C) ? sv_val[w][i] : 0xFFFFFFFFu;
        vmin_l = vmin_l < vb ? vmin_l : vb;
    }
#pragma unroll
    for (int off = 32; off >= 1; off >>= 1) {
        unsigned o2 = __shfl_xor(vmin_l, off, 64);
        vmin_l = vmin_l < o2 ? vmin_l : o2;
    }
    const unsigned Vmin = vmin_l;
    unsigned imin_l = 0xFFFFFFFFu;
    for (int s = 0; s < S; ++s) {
        int i = s * 64 + lane;
        unsigned vb = (i < (int)C) ? sv_val[w][i] : 0xFFFFFFFFu;
        unsigned mi = (i < (int)C) ? sv_idx[w][i] : 0xFFFFFFFFu;
        if (vb == Vmin && mi < imin_l) imin_l = mi;
    }
#pragma unroll
    for (int off = 32; off >= 1; off >>= 1) {
        unsigned o2 = __shfl_xor(imin_l, off, 64);
        imin_l = imin_l < o2 ? imin_l : o2;
    }
    const unsigned dropIdx = imin_l;

    int* o = idx_out + (size_t)gq * KNN;
    unsigned wbase = 0, tbase = 0;
    for (int s = 0; s < S; ++s) {
        int i = s * 64 + lane;
        unsigned vb = (i < (int)C) ? sv_val[w][i] : 0xFFFFFFFFu;
        unsigned mi = (i < (int)C) ? sv_idx[w][i] : 0xFFFFFFFFu;
        bool wk = (vb < Ts) && (mi != dropIdx);
        unsigned long long wm = __ballot(wk);
        if (wk) o[wbase + (unsigned)__popcll(wm & lt)] = (int)mi;
        wbase += (unsigned)__popcll(wm);
        bool tk = (vb == Ts);
        unsigned long long tm2 = __ballot(tk);
        if (tk) {
            unsigned tp = tbase + (unsigned)__popcll(tm2 & lt);
            if (tp < 64) tie_idx[w][tp] = mi;
        }
        tbase += (unsigned)__popcll(tm2);
    }
    unsigned tc = tbase > 64 ? 64 : tbase;
    if ((int)tc == need) {
        bool tk = (lane < (int)tc);
        unsigned mi2 = tk ? tie_idx[w][lane] : 0xFFFFFFFFu;
        tk = tk && (mi2 != dropIdx);
        unsigned long long m3 = __ballot(tk);
        if (tk) o[wbase + (unsigned)__popcll(m3 & lt)] = (int)mi2;
    } else if (lane == 0) {
        unsigned pos = wbase;
        for (int r = 0; r < need; ++r) {
            unsigned best = 0xFFFFFFFFu; int bj = 0;
            for (int j2 = 0; j2 < (int)tc; ++j2) {
                unsigned mi = tie_idx[w][j2];
                if (mi < best) { best = mi; bj = j2; }
            }
            tie_idx[w][bj] = 0xFFFFFFFFu;
            if (best != dropIdx) o[pos++] = (int)best;
        }
    }
}

// ---------------- gq_gemm: G = feat@W1a (f16), Q = feat@Wd + b1 (f16) -------------
__global__ __launch_bounds__(256, 4) void gq_gemm(const float* __restrict__ feat,
                                                  const _Float16* __restrict__ Wcf,
                                                  const float* __restrict__ b1,
                                                  _Float16* __restrict__ Gall,
                                                  _Float16* __restrict__ Qall) {
    __shared__ __align__(16) _Float16 st[4][16][136];
    const int t = threadIdx.x, w = t >> 6, lane = t & 63;
    const int quad = lane >> 4, l16 = lane & 15;
    const int m0 = blockIdx.x * 16;

    f16x8 a[2];
#pragma unroll
    for (int kk = 0; kk < 2; ++kk) {
        const float* ap = feat + (size_t)(m0 + l16) * 64 + kk * 32 + quad * 8;
        float4 a0 = *(const float4*)ap, a1 = *(const float4*)(ap + 4);
        f16x8 v;
        v[0] = (_Float16)a0.x; v[1] = (_Float16)a0.y; v[2] = (_Float16)a0.z; v[3] = (_Float16)a0.w;
        v[4] = (_Float16)a1.x; v[5] = (_Float16)a1.y; v[6] = (_Float16)a1.z; v[7] = (_Float16)a1.w;
        a[kk] = v;
    }
    f32x4 acc[8];
#pragma unroll
    for (int nt = 0; nt < 8; ++nt) acc[nt] = (f32x4){0.f, 0.f, 0.f, 0.f};
#pragma unroll
    for (int kk = 0; kk < 2; ++kk)
#pragma unroll
        for (int nt = 0; nt < 8; ++nt) {
            f16x8 bf = *(const f16x8*)(Wcf + (size_t)(((w * 8 + nt) * 2 + kk) * 64 + lane) * 8);
            acc[nt] = __builtin_amdgcn_mfma_f32_16x16x32_f16(a[kk], bf, acc[nt], 0, 0, 0);
        }

    const bool isQ = (w >= 2);
#pragma unroll
    for (int nt = 0; nt < 8; ++nt) {
        const int col = nt * 16 + l16;
        const float bias = isQ ? b1[(w - 2) * 128 + col] : 0.f;
#pragma unroll
        for (int r = 0; r < 4; ++r)
            st[w][quad * 4 + r][col] = (_Float16)(acc[nt][r] + bias);
    }
    __syncthreads();

    const int row = lane >> 2, c = lane & 3;
    const int m = m0 + row;
#pragma unroll
    for (int i = 0; i < 4; ++i) {
        const int col = c * 32 + i * 8;
        f16x8 v = *(const f16x8*)&st[w][row][col];
        if (!isQ) *(f16x8*)(Gall + (size_t)m * H2 + w * 128 + col) = v;
        else      *(f16x8*)(Qall + (size_t)m * H2 + (w - 2) * 128 + col) = v;
    }
}

// ---------------- fused_mlp9: out = mean_k gelu(gelu(G[idx]+Q) @ W2 + b2) -----------
// Changes vs mlp8 (it was beyond-L2-traffic-bound: 196 MB/dispatch = 2.07 TB/s,
// MfmaUtil 15%, VALUBusy 40%):
//  1. XCD-localized block swizzle: each XCD owns 4 whole batches -> its L2 only
//     pulls those batches' 512 KB G-slices (FETCH ~101 -> ~35 MB expected).
//  2. Coalesced output: stage per-wave results in LDS, one contiguous 4 KB
//     float4 store per block (WRITE ~90 -> ~18 MB expected; was 16-lane 64 B
//     partial-line fragments).
__global__ __launch_bounds__(256, 4) void fused_mlp9(const _Float16* __restrict__ Gall,
                                                     const _Float16* __restrict__ Qall,
                                                     const int* __restrict__ knn_idx,
                                                     const _Float16* __restrict__ W2f,
                                                     const float* __restrict__ b2,
                                                     float* __restrict__ out) {
    __shared__ __align__(16) _Float16 w2s[8192];    // 16 KB: one quarter (2 kk8) of W2f
    __shared__ __align__(16) float obuf[1024];      // 4 KB: block's 8x128 f32 output
    const int t = threadIdx.x, w = t >> 6, lane = t & 63;
    const int quad = lane >> 4, l16 = lane & 15;

    // XCD-aware swizzle: physical block p -> XCD p%8 (round-robin dispatch).
    // logical lb = (p%8)*512 + p/8 gives XCD x the contiguous range [512x, 512x+512)
    // = batches [4x, 4x+4). 4096 % 8 == 0 -> bijective.
    const int lb = ((blockIdx.x & 7) << 9) | (blockIdx.x >> 3);

    const int wave_id = lb * 4 + w;               // [0, 16384)
    const int q0 = wave_id * 2;                   // queries q0, q0+1
    const int b = q0 >> 10;
    const int nb0 = knn_idx[q0 * KNN + l16];
    const int nb1 = knn_idx[(q0 + 1) * KNN + l16];
    const _Float16* g0 = Gall + ((size_t)(b << 10) + nb0) * H2;
    const _Float16* g1 = Gall + ((size_t)(b << 10) + nb1) * H2;
    const _Float16* qq0 = Qall + (size_t)q0 * H2;
    const _Float16* qq1 = qq0 + H2;

    f32x4 acc[2][8];
#pragma unroll
    for (int tm = 0; tm < 2; ++tm)
#pragma unroll
        for (int nt = 0; nt < 8; ++nt) acc[tm][nt] = (f32x4){0.f, 0.f, 0.f, 0.f};

#pragma unroll
    for (int qtr = 0; qtr < 4; ++qtr) {
        if (qtr) __syncthreads();    // all waves done reading previous quarter
#pragma unroll
        for (int i = 0; i < 4; ++i) {
            f16x8 v = *(const f16x8*)(W2f + (size_t)(qtr * 8192 + i * 2048 + t * 8));
            *(f16x8*)&w2s[i * 2048 + t * 8] = v;
        }
        __syncthreads();

#pragma unroll
        for (int kl = 0; kl < 2; ++kl) {
            const int ho = (qtr * 2 + kl) * 32 + quad * 8;
            f16x8 gA = *(const f16x8*)(g0 + ho);
            f16x8 qA = *(const f16x8*)(qq0 + ho);
            f16x8 gB = *(const f16x8*)(g1 + ho);
            f16x8 qB = *(const f16x8*)(qq1 + ho);
            f16x8 a0 = act8(gA, qA);
            f16x8 a1 = act8(gB, qB);
            const _Float16* bb = &w2s[kl * 4096 + lane * 8];
#pragma unroll
            for (int nt = 0; nt < 8; ++nt) {
                f16x8 bf = *(const f16x8*)(bb + nt * 512);
                acc[0][nt] = __builtin_amdgcn_mfma_f32_16x16x32_f16(a0, bf, acc[0][nt], 0, 0, 0);
                acc[1][nt] = __builtin_amdgcn_mfma_f32_16x16x32_f16(a1, bf, acc[1][nt], 0, 0, 0);
            }
        }
    }

    // Epilogue: reduce over k (4 rows in-lane + quad dimension), stage to LDS,
    // then one contiguous 4 KB block store.
#pragma unroll
    for (int tm = 0; tm < 2; ++tm)
#pragma unroll
        for (int nt = 0; nt < 8; ++nt) {
            const float bias = b2[nt * 16 + l16];
            float s = 0.f;
#pragma unroll
            for (int r = 0; r < 4; ++r) s += gelu_poly(acc[tm][nt][r] + bias);
            s += __shfl_xor(s, 16, 64);
            s += __shfl_xor(s, 32, 64);
            if (quad == 0)
                obuf[(w * 2 + tm) * 128 + nt * 16 + l16] = s * 0.0625f;
        }
    __syncthreads();
    {
        // block covers queries [lb*8, lb*8+8) -> 4 KB contiguous in out
        float4 v = *(const float4*)&obuf[t * 4];
        *(float4*)(out + (size_t)lb * 1024 + t * 4) = v;
    }
}

extern "C" void kernel_launch(void* const* d_in, const int* in_sizes, int n_in,
                              void* d_out, int out_size, void* d_ws, size_t ws_size,
                              hipStream_t stream) {
    const float* points   = (const float*)d_in[0];
    const float* features = (const float*)d_in[1];
    const float* W1 = (const float*)d_in[2];
    const float* b1 = (const float*)d_in[3];
    const float* W2 = (const float*)d_in[4];
    const float* b2 = (const float*)d_in[5];
    float* out = (float*)d_out;

    const size_t IDX_B  = (size_t)BB * NN * KNN * 4;   // 2 MB
    const size_t WCF_B  = 512 * 64 * 2;                // 64 KB
    const size_t W2F_B  = 256 * 128 * 2;               // 64 KB
    const size_t G_B    = (size_t)BB * NN * H2 * 2;    // 16 MB

    int* knn_idx = (int*)d_ws;
    char* p = (char*)d_ws + IDX_B;
    _Float16* Wcf  = (_Float16*)p;  p += WCF_B;
    _Float16* W2f  = (_Float16*)p;  p += W2F_B;
    _Float16* Gall = (_Float16*)p;  p += G_B;
    _Float16* Qall = (_Float16*)p;                     // 16 MB -> total ~34.1 MB

    knn_prep<<<4112, 512, 0, stream>>>(points, knn_idx, W1, W2, Wcf, W2f);
    gq_gemm<<<2048, 256, 0, stream>>>(features, Wcf, b1, Gall, Qall);
    fused_mlp9<<<4096, 256, 0, stream>>>(Gall, Qall, knn_idx, W2f, b2, out);
}

// Round 4
// 192.789 us; speedup vs baseline: 1.0722x; 1.0395x over previous
//
#include <hip/hip_runtime.h>
#include <math.h>

#define BB 32
#define NN 1024
#define FF 64
#define PP 128
#define KNN 16
#define H2 256  // 2P
#define F2 128  // 2F
#define KSEL 17
#define SVCAP 272

typedef float f32x4 __attribute__((ext_vector_type(4)));
typedef _Float16 f16x8 __attribute__((ext_vector_type(8)));

// ---- transcendental-free gelu: y = x * (0.5 + xc*P(xc^2)), xc = clamp(x, +-3.3)
// u = 0.5 + xc*P(xc^2) is monotone with range [5e-4, 0.9995] over the clamped
// domain, so the [0,1] clamp is redundant (removed; saves 2 ops per call).
#define GC1 0.39616247f
#define GC3 -0.05891477f
#define GC5 0.00563735f
#define GC7 -2.10439e-4f
#define GXC 3.2988f

__device__ __forceinline__ float gelu_poly(float x) {
    float xc = __builtin_amdgcn_fmed3f(x, -GXC, GXC);
    float s = xc * xc;
    float t = fmaf(s, GC7, GC5);
    t = fmaf(s, t, GC3);
    t = fmaf(s, t, GC1);
    float u = fmaf(xc, t, 0.5f);
    return x * u;
}

__device__ __forceinline__ f16x8 splat8(float f) {
    _Float16 h = (_Float16)f;
    f16x8 v = {h, h, h, h, h, h, h, h};
    return v;
}

// packed-f16 activation for 8 elements: gelu(g + q); lowers to v_pk_{add,mul,fma,min,max}_f16
// 9 vector ops (36 instrs) per call.
__device__ __forceinline__ f16x8 act8(f16x8 gv, f16x8 qv) {
    const f16x8 XL = splat8(-GXC), XH = splat8(GXC);
    const f16x8 C1 = splat8(GC1), C3 = splat8(GC3), C5 = splat8(GC5), C7 = splat8(GC7);
    const f16x8 HF = splat8(0.5f);
    f16x8 x  = gv + qv;
    f16x8 xc = __builtin_elementwise_min(__builtin_elementwise_max(x, XL), XH);
    f16x8 s  = xc * xc;
    f16x8 t  = s * C7 + C5;
    t = s * t + C3;
    t = s * t + C1;
    f16x8 u = xc * t + HF;
    return x * u;
}

// ------- Kernel A: set-based kNN (blocks 0..4095) + weight-frag prep (4096..4111) ---
__global__ __launch_bounds__(512, 8) void knn_prep(const float* __restrict__ points,
                                                   int* __restrict__ idx_out,
                                                   const float* __restrict__ W1,
                                                   const float* __restrict__ W2,
                                                   _Float16* __restrict__ Wcf,
                                                   _Float16* __restrict__ W2f) {
    if (blockIdx.x >= 4096) {
        // ---- prep path: fragment-swizzled Wcf (gq_gemm B) + W2f (fused B), f16 ----
        int tid = (blockIdx.x - 4096) * 512 + threadIdx.x;   // 0..8191
        if (tid < 4096) {
            const int lane = tid & 63, quad = lane >> 4, l16 = lane & 15;
            const int kk = (tid >> 6) & 1, n_tile = tid >> 7;
            const int n = n_tile * 16 + l16;
            const int kb = kk * 32 + quad * 8;
            f16x8 v;
#pragma unroll
            for (int j = 0; j < 8; ++j) {
                const int k = kb + j;
                float x = (n < 256) ? W1[k * 256 + n]
                                    : (W1[(64 + k) * 256 + (n - 256)] - W1[k * 256 + (n - 256)]);
                v[j] = (_Float16)x;
            }
            *(f16x8*)(Wcf + (size_t)tid * 8) = v;
        } else {
            const int t2 = tid - 4096;
            const int lane = t2 & 63, quad = lane >> 4, l16 = lane & 15;
            const int nt = (t2 >> 6) & 7, kk8 = t2 >> 9;
            const int p = nt * 16 + l16;
            const int hb = kk8 * 32 + quad * 8;
            f16x8 v;
#pragma unroll
            for (int j = 0; j < 8; ++j) v[j] = (_Float16)W2[(size_t)(hb + j) * PP + p];
            *(f16x8*)(W2f + (size_t)t2 * 8) = v;
        }
        return;
    }

    // SoA point storage: stride-4B LDS reads are bank-conflict-free.
    __shared__ float px[NN], py[NN], pz[NN], rr[NN];
    __shared__ unsigned sv_val[8][SVCAP];
    __shared__ unsigned sv_idx[8][SVCAP];
    __shared__ unsigned tie_idx[8][64];

    const int t = threadIdx.x;
    const int w = t >> 6, lane = t & 63;
    const int b = blockIdx.x >> 7;
    const int q0 = (blockIdx.x & 127) * 8;
    const float* pb = points + (size_t)b * NN * 3;
    const unsigned long long lt = (1ull << lane) - 1ull;

    for (int i = t; i < NN; i += 512) {
        float x = pb[3 * i], y = pb[3 * i + 1], z = pb[3 * i + 2];
        px[i] = x; py[i] = y; pz[i] = z;
        rr[i] = __fadd_rn(__fadd_rn(__fmul_rn(x, x), __fmul_rn(y, y)), __fmul_rn(z, z));
    }
    __syncthreads();

    const int qn = q0 + w;
    const int gq = b * NN + qn;
    const float qx = px[qn], qy = py[qn], qz = pz[qn], qw = rr[qn];

    float D[16];
#pragma unroll
    for (int j = 0; j < 16; ++j) {
        const int m = j * 64 + lane;
        float dot = __fadd_rn(__fadd_rn(__fmul_rn(qx, px[m]), __fmul_rn(qy, py[m])),
                              __fmul_rn(qz, pz[m]));
        D[j] = __fadd_rn(__fadd_rn(__fsub_rn(qw, __fmul_rn(2.0f, dot)), rr[m]), 1e-5f);
    }

    float mnf = D[0];
#pragma unroll
    for (int j = 1; j < 16; ++j) mnf = fminf(mnf, D[j]);
    const unsigned mbits = __float_as_uint(mnf);

    // T_ub via 16-round radix on the HIGH 16 bits of the lane-mins.
    const unsigned mhi = mbits >> 16;
    unsigned Thi = 0;
#pragma unroll
    for (int bit = 15; bit >= 0; --bit) {
        unsigned cand = Thi | (1u << bit);
        int cnt = __popcll(__ballot(mhi < cand));
        if (cnt < KSEL) Thi = cand;
    }
    const unsigned T = (Thi << 16) | 0xFFFFu;

    unsigned base = 0;
#pragma unroll
    for (int j = 0; j < 16; ++j) {
        unsigned vb = __float_as_uint(D[j]);
        bool keep = (vb <= T);
        unsigned long long m = __ballot(keep);
        if (keep) {
            unsigned pos = base + (unsigned)__popcll(m & lt);
            if (pos < SVCAP) { sv_val[w][pos] = vb; sv_idx[w][pos] = j * 64 + lane; }
        }
        base += (unsigned)__popcll(m);
    }
    unsigned C = base > SVCAP ? SVCAP : base;
    const int S = (int)((C + 63) >> 6);

    unsigned Ts = 0;
    if (S == 1) {
        unsigned xv0 = (lane < (int)C) ? sv_val[w][lane] : 0xFFFFFFFFu;
#pragma unroll
        for (int bit = 31; bit >= 0; --bit) {
            unsigned cand = Ts | (1u << bit);
            int cnt = __popcll(__ballot(xv0 < cand));
            if (cnt < KSEL) Ts = cand;
        }
    } else {
        for (int bit = 31; bit >= 0; --bit) {
            unsigned cand = Ts | (1u << bit);
            int cnt = 0;
            for (int s = 0; s < S; ++s) {
                int i = s * 64 + lane;
                unsigned vb = (i < (int)C) ? sv_val[w][i] : 0xFFFFFFFFu;
                cnt += __popcll(__ballot(vb < cand));
            }
            if (cnt < KSEL) Ts = cand;
        }
    }

    int L = 0;
    for (int s = 0; s < S; ++s) {
        int i = s * 64 + lane;
        unsigned vb = (i < (int)C) ? sv_val[w][i] : 0xFFFFFFFFu;
        L += __popcll(__ballot(vb < Ts));
    }
    const int need = KSEL - L;

    unsigned vmin_l = 0xFFFFFFFFu;
    for (int s = 0; s < S; ++s) {
        int i = s * 64 + lane;
        unsigned vb = (i < (int)C) ? sv_val[w][i] : 0xFFFFFFFFu;
        vmin_l = vmin_l < vb ? vmin_l : vb;
    }
#pragma unroll
    for (int off = 32; off >= 1; off >>= 1) {
        unsigned o2 = __shfl_xor(vmin_l, off, 64);
        vmin_l = vmin_l < o2 ? vmin_l : o2;
    }
    const unsigned Vmin = vmin_l;
    unsigned imin_l = 0xFFFFFFFFu;
    for (int s = 0; s < S; ++s) {
        int i = s * 64 + lane;
        unsigned vb = (i < (int)C) ? sv_val[w][i] : 0xFFFFFFFFu;
        unsigned mi = (i < (int)C) ? sv_idx[w][i] : 0xFFFFFFFFu;
        if (vb == Vmin && mi < imin_l) imin_l = mi;
    }
#pragma unroll
    for (int off = 32; off >= 1; off >>= 1) {
        unsigned o2 = __shfl_xor(imin_l, off, 64);
        imin_l = imin_l < o2 ? imin_l : o2;
    }
    const unsigned dropIdx = imin_l;

    int* o = idx_out + (size_t)gq * KNN;
    unsigned wbase = 0, tbase = 0;
    for (int s = 0; s < S; ++s) {
        int i = s * 64 + lane;
        unsigned vb = (i < (int)C) ? sv_val[w][i] : 0xFFFFFFFFu;
        unsigned mi = (i < (int)C) ? sv_idx[w][i] : 0xFFFFFFFFu;
        bool wk = (vb < Ts) && (mi != dropIdx);
        unsigned long long wm = __ballot(wk);
        if (wk) o[wbase + (unsigned)__popcll(wm & lt)] = (int)mi;
        wbase += (unsigned)__popcll(wm);
        bool tk = (vb == Ts);
        unsigned long long tm2 = __ballot(tk);
        if (tk) {
            unsigned tp = tbase + (unsigned)__popcll(tm2 & lt);
            if (tp < 64) tie_idx[w][tp] = mi;
        }
        tbase += (unsigned)__popcll(tm2);
    }
    unsigned tc = tbase > 64 ? 64 : tbase;
    if ((int)tc == need) {
        bool tk = (lane < (int)tc);
        unsigned mi2 = tk ? tie_idx[w][lane] : 0xFFFFFFFFu;
        tk = tk && (mi2 != dropIdx);
        unsigned long long m3 = __ballot(tk);
        if (tk) o[wbase + (unsigned)__popcll(m3 & lt)] = (int)mi2;
    } else if (lane == 0) {
        unsigned pos = wbase;
        for (int r = 0; r < need; ++r) {
            unsigned best = 0xFFFFFFFFu; int bj = 0;
            for (int j2 = 0; j2 < (int)tc; ++j2) {
                unsigned mi = tie_idx[w][j2];
                if (mi < best) { best = mi; bj = j2; }
            }
            tie_idx[w][bj] = 0xFFFFFFFFu;
            if (best != dropIdx) o[pos++] = (int)best;
        }
    }
}

// ---------------- gq_gemm: G = feat@W1a (f16), Q = feat@Wd + b1 (f16) -------------
__global__ __launch_bounds__(256, 4) void gq_gemm(const float* __restrict__ feat,
                                                  const _Float16* __restrict__ Wcf,
                                                  const float* __restrict__ b1,
                                                  _Float16* __restrict__ Gall,
                                                  _Float16* __restrict__ Qall) {
    __shared__ __align__(16) _Float16 st[4][16][136];
    const int t = threadIdx.x, w = t >> 6, lane = t & 63;
    const int quad = lane >> 4, l16 = lane & 15;
    const int m0 = blockIdx.x * 16;

    f16x8 a[2];
#pragma unroll
    for (int kk = 0; kk < 2; ++kk) {
        const float* ap = feat + (size_t)(m0 + l16) * 64 + kk * 32 + quad * 8;
        float4 a0 = *(const float4*)ap, a1 = *(const float4*)(ap + 4);
        f16x8 v;
        v[0] = (_Float16)a0.x; v[1] = (_Float16)a0.y; v[2] = (_Float16)a0.z; v[3] = (_Float16)a0.w;
        v[4] = (_Float16)a1.x; v[5] = (_Float16)a1.y; v[6] = (_Float16)a1.z; v[7] = (_Float16)a1.w;
        a[kk] = v;
    }
    f32x4 acc[8];
#pragma unroll
    for (int nt = 0; nt < 8; ++nt) acc[nt] = (f32x4){0.f, 0.f, 0.f, 0.f};
#pragma unroll
    for (int kk = 0; kk < 2; ++kk)
#pragma unroll
        for (int nt = 0; nt < 8; ++nt) {
            f16x8 bf = *(const f16x8*)(Wcf + (size_t)(((w * 8 + nt) * 2 + kk) * 64 + lane) * 8);
            acc[nt] = __builtin_amdgcn_mfma_f32_16x16x32_f16(a[kk], bf, acc[nt], 0, 0, 0);
        }

    const bool isQ = (w >= 2);
#pragma unroll
    for (int nt = 0; nt < 8; ++nt) {
        const int col = nt * 16 + l16;
        const float bias = isQ ? b1[(w - 2) * 128 + col] : 0.f;
#pragma unroll
        for (int r = 0; r < 4; ++r)
            st[w][quad * 4 + r][col] = (_Float16)(acc[nt][r] + bias);
    }
    __syncthreads();

    const int row = lane >> 2, c = lane & 3;
    const int m = m0 + row;
#pragma unroll
    for (int i = 0; i < 4; ++i) {
        const int col = c * 32 + i * 8;
        f16x8 v = *(const f16x8*)&st[w][row][col];
        if (!isQ) *(f16x8*)(Gall + (size_t)m * H2 + w * 128 + col) = v;
        else      *(f16x8*)(Qall + (size_t)m * H2 + (w - 2) * 128 + col) = v;
    }
}

// ---------------- fused_mlp10: out = mean_k gelu(gelu(G[idx]+Q) @ W2 + b2) ----------
// Round-3 post-mortem: traffic cut (196->121 MB) gave ~0 speedup -> latency/stall
// bound, residency register-capped at ~16 waves/CU (64 VGPR + 64 AGPR acc).
// This version attacks stalls:
//  - 512-thr blocks (8 waves), W2f staged in TWO 32 KB halves -> 5 barriers/block
//    (was 8 per 4 waves), staging work per wave cut 4x.
//  - barrier-free compute region per half (2 qtr x 2 kl) -> compiler hoists all
//    16 gather loads of the half ahead of the act/MFMA chains.
//  - obuf aliases w2s after a barrier (LDS stays 32 KB).
__global__ __launch_bounds__(512, 4) void fused_mlp10(const _Float16* __restrict__ Gall,
                                                      const _Float16* __restrict__ Qall,
                                                      const int* __restrict__ knn_idx,
                                                      const _Float16* __restrict__ W2f,
                                                      const float* __restrict__ b2,
                                                      float* __restrict__ out) {
    __shared__ __align__(16) _Float16 w2s[16384];   // 32 KB: one half (2 qtr) of W2f
    const int t = threadIdx.x, w = t >> 6, lane = t & 63;
    const int quad = lane >> 4, l16 = lane & 15;

    // XCD-aware swizzle: 2048 blocks, XCD x owns logical [256x, 256x+256) = 4 batches.
    const int lb = ((blockIdx.x & 7) << 8) | (blockIdx.x >> 3);

    const int q0 = (lb * 8 + w) * 2;              // queries q0, q0+1; block covers 16
    const int b = q0 >> 10;
    const int nb0 = knn_idx[q0 * KNN + l16];
    const int nb1 = knn_idx[(q0 + 1) * KNN + l16];
    const _Float16* g0 = Gall + ((size_t)(b << 10) + nb0) * H2;
    const _Float16* g1 = Gall + ((size_t)(b << 10) + nb1) * H2;
    const _Float16* qq0 = Qall + (size_t)q0 * H2;
    const _Float16* qq1 = qq0 + H2;

    f32x4 acc[2][8];
#pragma unroll
    for (int tm = 0; tm < 2; ++tm)
#pragma unroll
        for (int nt = 0; nt < 8; ++nt) acc[tm][nt] = (f32x4){0.f, 0.f, 0.f, 0.f};

#pragma unroll
    for (int h = 0; h < 2; ++h) {
        if (h) __syncthreads();      // all waves done reading half 0
#pragma unroll
        for (int i = 0; i < 4; ++i) {
            f16x8 v = *(const f16x8*)(W2f + (size_t)(h * 16384 + i * 4096 + t * 8));
            *(f16x8*)&w2s[i * 4096 + t * 8] = v;
        }
        __syncthreads();

        // barrier-free compute region: 2 quarters x 2 kl
#pragma unroll
        for (int ql = 0; ql < 2; ++ql)
#pragma unroll
            for (int kl = 0; kl < 2; ++kl) {
                const int ho = (((h * 2 + ql) * 2) + kl) * 32 + quad * 8;
                f16x8 gA = *(const f16x8*)(g0 + ho);
                f16x8 qA = *(const f16x8*)(qq0 + ho);
                f16x8 gB = *(const f16x8*)(g1 + ho);
                f16x8 qB = *(const f16x8*)(qq1 + ho);
                f16x8 a0 = act8(gA, qA);
                f16x8 a1 = act8(gB, qB);
                const _Float16* bb = &w2s[(ql * 2 + kl) * 4096 + lane * 8];
#pragma unroll
                for (int nt = 0; nt < 8; ++nt) {
                    f16x8 bf = *(const f16x8*)(bb + nt * 512);
                    acc[0][nt] = __builtin_amdgcn_mfma_f32_16x16x32_f16(a0, bf, acc[0][nt], 0, 0, 0);
                    acc[1][nt] = __builtin_amdgcn_mfma_f32_16x16x32_f16(a1, bf, acc[1][nt], 0, 0, 0);
                }
            }
    }

    // Epilogue: w2s no longer needed -> alias obuf into it (after a barrier).
    __syncthreads();
    float* obuf = (float*)w2s;       // 8 KB used of 32 KB
#pragma unroll
    for (int tm = 0; tm < 2; ++tm)
#pragma unroll
        for (int nt = 0; nt < 8; ++nt) {
            const float bias = b2[nt * 16 + l16];
            float s = 0.f;
#pragma unroll
            for (int r = 0; r < 4; ++r) s += gelu_poly(acc[tm][nt][r] + bias);
            s += __shfl_xor(s, 16, 64);
            s += __shfl_xor(s, 32, 64);
            if (quad == 0)
                obuf[(w * 2 + tm) * 128 + nt * 16 + l16] = s * 0.0625f;
        }
    __syncthreads();
    {
        // block covers queries [lb*16, lb*16+16) -> 8 KB contiguous in out
        float4 v = *(const float4*)&obuf[t * 4];
        *(float4*)(out + (size_t)lb * 2048 + t * 4) = v;
    }
}

extern "C" void kernel_launch(void* const* d_in, const int* in_sizes, int n_in,
                              void* d_out, int out_size, void* d_ws, size_t ws_size,
                              hipStream_t stream) {
    const float* points   = (const float*)d_in[0];
    const float* features = (const float*)d_in[1];
    const float* W1 = (const float*)d_in[2];
    const float* b1 = (const float*)d_in[3];
    const float* W2 = (const float*)d_in[4];
    const float* b2 = (const float*)d_in[5];
    float* out = (float*)d_out;

    const size_t IDX_B  = (size_t)BB * NN * KNN * 4;   // 2 MB
    const size_t WCF_B  = 512 * 64 * 2;                // 64 KB
    const size_t W2F_B  = 256 * 128 * 2;               // 64 KB
    const size_t G_B    = (size_t)BB * NN * H2 * 2;    // 16 MB

    int* knn_idx = (int*)d_ws;
    char* p = (char*)d_ws + IDX_B;
    _Float16* Wcf  = (_Float16*)p;  p += WCF_B;
    _Float16* W2f  = (_Float16*)p;  p += W2F_B;
    _Float16* Gall = (_Float16*)p;  p += G_B;
    _Float16* Qall = (_Float16*)p;                     // 16 MB -> total ~34.1 MB

    knn_prep<<<4112, 512, 0, stream>>>(points, knn_idx, W1, W2, Wcf, W2f);
    gq_gemm<<<2048, 256, 0, stream>>>(features, Wcf, b1, Gall, Qall);
    fused_mlp10<<<2048, 512, 0, stream>>>(Gall, Qall, knn_idx, W2f, b2, out);
}

// Round 5
// 190.778 us; speedup vs baseline: 1.0835x; 1.0105x over previous
//
#include <hip/hip_runtime.h>
#include <math.h>

#define BB 32
#define NN 1024
#define FF 64
#define PP 128
#define KNN 16
#define H2 256  // 2P
#define F2 128  // 2F
#define KSEL 17
#define SVCAP 272

typedef float f32x4 __attribute__((ext_vector_type(4)));
typedef _Float16 f16x8 __attribute__((ext_vector_type(8)));

// ---- transcendental-free gelu: y = x * (0.5 + xc*P(xc^2)), xc = clamp(x, +-3.3)
#define GC1 0.39616247f
#define GC3 -0.05891477f
#define GC5 0.00563735f
#define GC7 -2.10439e-4f
#define GXC 3.2988f

__device__ __forceinline__ float gelu_poly(float x) {
    float xc = __builtin_amdgcn_fmed3f(x, -GXC, GXC);
    float s = xc * xc;
    float t = fmaf(s, GC7, GC5);
    t = fmaf(s, t, GC3);
    t = fmaf(s, t, GC1);
    float u = fmaf(xc, t, 0.5f);
    return x * u;
}

__device__ __forceinline__ f16x8 splat8(float f) {
    _Float16 h = (_Float16)f;
    f16x8 v = {h, h, h, h, h, h, h, h};
    return v;
}

// packed-f16 activation for 8 elements: gelu(g + q); v_pk_{add,mul,fma,min,max}_f16
__device__ __forceinline__ f16x8 act8(f16x8 gv, f16x8 qv) {
    const f16x8 XL = splat8(-GXC), XH = splat8(GXC);
    const f16x8 C1 = splat8(GC1), C3 = splat8(GC3), C5 = splat8(GC5), C7 = splat8(GC7);
    const f16x8 HF = splat8(0.5f);
    f16x8 x  = gv + qv;
    f16x8 xc = __builtin_elementwise_min(__builtin_elementwise_max(x, XL), XH);
    f16x8 s  = xc * xc;
    f16x8 t  = s * C7 + C5;
    t = s * t + C3;
    t = s * t + C1;
    f16x8 u = xc * t + HF;
    return x * u;
}

// ------- prep_weights: fragment-swizzled Wcf (gq B-operand) + W2f (fused B) --------
// Tiny (16 blocks); runs before knn_gq so both consumers see its output.
__global__ __launch_bounds__(512) void prep_weights(const float* __restrict__ W1,
                                                    const float* __restrict__ W2,
                                                    _Float16* __restrict__ Wcf,
                                                    _Float16* __restrict__ W2f) {
    int tid = blockIdx.x * 512 + threadIdx.x;   // 0..8191
    if (tid < 4096) {
        const int lane = tid & 63, quad = lane >> 4, l16 = lane & 15;
        const int kk = (tid >> 6) & 1, n_tile = tid >> 7;
        const int n = n_tile * 16 + l16;
        const int kb = kk * 32 + quad * 8;
        f16x8 v;
#pragma unroll
        for (int j = 0; j < 8; ++j) {
            const int k = kb + j;
            float x = (n < 256) ? W1[k * 256 + n]
                                : (W1[(64 + k) * 256 + (n - 256)] - W1[k * 256 + (n - 256)]);
            v[j] = (_Float16)x;
        }
        *(f16x8*)(Wcf + (size_t)tid * 8) = v;
    } else {
        const int t2 = tid - 4096;
        const int lane = t2 & 63, quad = lane >> 4, l16 = lane & 15;
        const int nt = (t2 >> 6) & 7, kk8 = t2 >> 9;
        const int p = nt * 16 + l16;
        const int hb = kk8 * 32 + quad * 8;
        f16x8 v;
#pragma unroll
        for (int j = 0; j < 8; ++j) v[j] = (_Float16)W2[(size_t)(hb + j) * PP + p];
        *(f16x8*)(W2f + (size_t)t2 * 8) = v;
    }
}

// ------- knn_gq: blocks 0..4095 = set-based kNN; 4096..5119 = G/Q GEMM -------------
// kNN and gq are mutually independent (kNN reads points; gq reads feat + Wcf from
// the earlier prep launch), so merging lets gq fill CU slots as kNN blocks drain
// instead of serializing behind the full kNN grid.
__global__ __launch_bounds__(512, 8) void knn_gq(const float* __restrict__ points,
                                                 int* __restrict__ idx_out,
                                                 const float* __restrict__ feat,
                                                 const _Float16* __restrict__ Wcf,
                                                 const float* __restrict__ b1,
                                                 _Float16* __restrict__ Gall,
                                                 _Float16* __restrict__ Qall) {
    // one LDS arena, aliased per path (kNN: 35840 B, gq: 34816 B)
    __shared__ __align__(16) unsigned char smem[35840];
    const int t = threadIdx.x;

    if (blockIdx.x >= 4096) {
        // ---------------- gq path: 32 rows/block, 8 waves (two 16-row subtiles) ----
        _Float16 (*st)[16][136] = (_Float16(*)[16][136])smem;
        const int w8 = t >> 6, lane = t & 63;
        const int w4 = w8 & 3;                       // role within subtile
        const int quad = lane >> 4, l16 = lane & 15;
        const int gb = blockIdx.x - 4096;            // 0..1023
        const int m0 = gb * 32 + (w8 >> 2) * 16;

        f16x8 a[2];
#pragma unroll
        for (int kk = 0; kk < 2; ++kk) {
            const float* ap = feat + (size_t)(m0 + l16) * 64 + kk * 32 + quad * 8;
            float4 a0 = *(const float4*)ap, a1 = *(const float4*)(ap + 4);
            f16x8 v;
            v[0] = (_Float16)a0.x; v[1] = (_Float16)a0.y; v[2] = (_Float16)a0.z; v[3] = (_Float16)a0.w;
            v[4] = (_Float16)a1.x; v[5] = (_Float16)a1.y; v[6] = (_Float16)a1.z; v[7] = (_Float16)a1.w;
            a[kk] = v;
        }
        f32x4 acc[8];
#pragma unroll
        for (int nt = 0; nt < 8; ++nt) acc[nt] = (f32x4){0.f, 0.f, 0.f, 0.f};
#pragma unroll
        for (int kk = 0; kk < 2; ++kk)
#pragma unroll
            for (int nt = 0; nt < 8; ++nt) {
                f16x8 bf = *(const f16x8*)(Wcf + (size_t)(((w4 * 8 + nt) * 2 + kk) * 64 + lane) * 8);
                acc[nt] = __builtin_amdgcn_mfma_f32_16x16x32_f16(a[kk], bf, acc[nt], 0, 0, 0);
            }

        const bool isQ = (w4 >= 2);
#pragma unroll
        for (int nt = 0; nt < 8; ++nt) {
            const int col = nt * 16 + l16;
            const float bias = isQ ? b1[(w4 - 2) * 128 + col] : 0.f;
#pragma unroll
            for (int r = 0; r < 4; ++r)
                st[w8][quad * 4 + r][col] = (_Float16)(acc[nt][r] + bias);
        }
        __syncthreads();

        const int row = lane >> 2, c = lane & 3;
        const int m = m0 + row;
#pragma unroll
        for (int i = 0; i < 4; ++i) {
            const int col = c * 32 + i * 8;
            f16x8 v = *(const f16x8*)&st[w8][row][col];
            if (!isQ) *(f16x8*)(Gall + (size_t)m * H2 + w4 * 128 + col) = v;
            else      *(f16x8*)(Qall + (size_t)m * H2 + (w4 - 2) * 128 + col) = v;
        }
        return;
    }

    // ---------------- kNN path (unchanged algorithm; LDS via arena) ----------------
    float* px = (float*)smem;                                   // 4 KB
    float* py = px + NN;                                        // 4 KB
    float* pz = py + NN;                                        // 4 KB
    float* rr = pz + NN;                                        // 4 KB
    unsigned (*sv_val)[SVCAP] = (unsigned(*)[SVCAP])(smem + 16384);   // 8704 B
    unsigned (*sv_idx)[SVCAP] = (unsigned(*)[SVCAP])(smem + 25088);   // 8704 B
    unsigned (*tie_idx)[64]   = (unsigned(*)[64])(smem + 33792);      // 2048 B

    const int w = t >> 6, lane = t & 63;
    const int b = blockIdx.x >> 7;
    const int q0 = (blockIdx.x & 127) * 8;
    const float* pb = points + (size_t)b * NN * 3;
    const unsigned long long lt = (1ull << lane) - 1ull;

    for (int i = t; i < NN; i += 512) {
        float x = pb[3 * i], y = pb[3 * i + 1], z = pb[3 * i + 2];
        px[i] = x; py[i] = y; pz[i] = z;
        rr[i] = __fadd_rn(__fadd_rn(__fmul_rn(x, x), __fmul_rn(y, y)), __fmul_rn(z, z));
    }
    __syncthreads();

    const int qn = q0 + w;
    const int gq = b * NN + qn;
    const float qx = px[qn], qy = py[qn], qz = pz[qn], qw = rr[qn];

    float D[16];
#pragma unroll
    for (int j = 0; j < 16; ++j) {
        const int m = j * 64 + lane;
        float dot = __fadd_rn(__fadd_rn(__fmul_rn(qx, px[m]), __fmul_rn(qy, py[m])),
                              __fmul_rn(qz, pz[m]));
        D[j] = __fadd_rn(__fadd_rn(__fsub_rn(qw, __fmul_rn(2.0f, dot)), rr[m]), 1e-5f);
    }

    float mnf = D[0];
#pragma unroll
    for (int j = 1; j < 16; ++j) mnf = fminf(mnf, D[j]);
    const unsigned mbits = __float_as_uint(mnf);

    // T_ub via 16-round radix on the HIGH 16 bits of the lane-mins.
    const unsigned mhi = mbits >> 16;
    unsigned Thi = 0;
#pragma unroll
    for (int bit = 15; bit >= 0; --bit) {
        unsigned cand = Thi | (1u << bit);
        int cnt = __popcll(__ballot(mhi < cand));
        if (cnt < KSEL) Thi = cand;
    }
    const unsigned T = (Thi << 16) | 0xFFFFu;

    unsigned base = 0;
#pragma unroll
    for (int j = 0; j < 16; ++j) {
        unsigned vb = __float_as_uint(D[j]);
        bool keep = (vb <= T);
        unsigned long long m = __ballot(keep);
        if (keep) {
            unsigned pos = base + (unsigned)__popcll(m & lt);
            if (pos < SVCAP) { sv_val[w][pos] = vb; sv_idx[w][pos] = j * 64 + lane; }
        }
        base += (unsigned)__popcll(m);
    }
    unsigned C = base > SVCAP ? SVCAP : base;
    const int S = (int)((C + 63) >> 6);

    unsigned Ts = 0;
    if (S == 1) {
        unsigned xv0 = (lane < (int)C) ? sv_val[w][lane] : 0xFFFFFFFFu;
#pragma unroll
        for (int bit = 31; bit >= 0; --bit) {
            unsigned cand = Ts | (1u << bit);
            int cnt = __popcll(__ballot(xv0 < cand));
            if (cnt < KSEL) Ts = cand;
        }
    } else {
        for (int bit = 31; bit >= 0; --bit) {
            unsigned cand = Ts | (1u << bit);
            int cnt = 0;
            for (int s = 0; s < S; ++s) {
                int i = s * 64 + lane;
                unsigned vb = (i < (int)C) ? sv_val[w][i] : 0xFFFFFFFFu;
                cnt += __popcll(__ballot(vb < cand));
            }
            if (cnt < KSEL) Ts = cand;
        }
    }

    int L = 0;
    for (int s = 0; s < S; ++s) {
        int i = s * 64 + lane;
        unsigned vb = (i < (int)C) ? sv_val[w][i] : 0xFFFFFFFFu;
        L += __popcll(__ballot(vb < Ts));
    }
    const int need = KSEL - L;

    unsigned vmin_l = 0xFFFFFFFFu;
    for (int s = 0; s < S; ++s) {
        int i = s * 64 + lane;
        unsigned vb = (i < (int)C) ? sv_val[w][i] : 0xFFFFFFFFu;
        vmin_l = vmin_l < vb ? vmin_l : vb;
    }
#pragma unroll
    for (int off = 32; off >= 1; off >>= 1) {
        unsigned o2 = __shfl_xor(vmin_l, off, 64);
        vmin_l = vmin_l < o2 ? vmin_l : o2;
    }
    const unsigned Vmin = vmin_l;
    unsigned imin_l = 0xFFFFFFFFu;
    for (int s = 0; s < S; ++s) {
        int i = s * 64 + lane;
        unsigned vb = (i < (int)C) ? sv_val[w][i] : 0xFFFFFFFFu;
        unsigned mi = (i < (int)C) ? sv_idx[w][i] : 0xFFFFFFFFu;
        if (vb == Vmin && mi < imin_l) imin_l = mi;
    }
#pragma unroll
    for (int off = 32; off >= 1; off >>= 1) {
        unsigned o2 = __shfl_xor(imin_l, off, 64);
        imin_l = imin_l < o2 ? imin_l : o2;
    }
    const unsigned dropIdx = imin_l;

    int* o = idx_out + (size_t)gq * KNN;
    unsigned wbase = 0, tbase = 0;
    for (int s = 0; s < S; ++s) {
        int i = s * 64 + lane;
        unsigned vb = (i < (int)C) ? sv_val[w][i] : 0xFFFFFFFFu;
        unsigned mi = (i < (int)C) ? sv_idx[w][i] : 0xFFFFFFFFu;
        bool wk = (vb < Ts) && (mi != dropIdx);
        unsigned long long wm = __ballot(wk);
        if (wk) o[wbase + (unsigned)__popcll(wm & lt)] = (int)mi;
        wbase += (unsigned)__popcll(wm);
        bool tk = (vb == Ts);
        unsigned long long tm2 = __ballot(tk);
        if (tk) {
            unsigned tp = tbase + (unsigned)__popcll(tm2 & lt);
            if (tp < 64) tie_idx[w][tp] = mi;
        }
        tbase += (unsigned)__popcll(tm2);
    }
    unsigned tc = tbase > 64 ? 64 : tbase;
    if ((int)tc == need) {
        bool tk = (lane < (int)tc);
        unsigned mi2 = tk ? tie_idx[w][lane] : 0xFFFFFFFFu;
        tk = tk && (mi2 != dropIdx);
        unsigned long long m3 = __ballot(tk);
        if (tk) o[wbase + (unsigned)__popcll(m3 & lt)] = (int)mi2;
    } else if (lane == 0) {
        unsigned pos = wbase;
        for (int r = 0; r < need; ++r) {
            unsigned best = 0xFFFFFFFFu; int bj = 0;
            for (int j2 = 0; j2 < (int)tc; ++j2) {
                unsigned mi = tie_idx[w][j2];
                if (mi < best) { best = mi; bj = j2; }
            }
            tie_idx[w][bj] = 0xFFFFFFFFu;
            if (best != dropIdx) o[pos++] = (int)best;
        }
    }
}

// ---------------- fused_mlp11: out = mean_k gelu(gelu(G[idx]+Q) @ W2 + b2) ----------
// Round-4 post-mortem: traffic compulsory (35 MB), VALUBusy 48%, Occ 38% -> still
// barrier/latency bound. This version stages ALL 64 KB of W2f once (LDS 64 KB ->
// still 2 blocks/CU, same as the 128-reg cap, so zero occupancy cost), cutting
// barriers 5 -> 3 and making the whole 8-region compute one barrier-free region
// so all 32 per-wave gather loads can hoist/pipeline.
__global__ __launch_bounds__(512, 4) void fused_mlp11(const _Float16* __restrict__ Gall,
                                                      const _Float16* __restrict__ Qall,
                                                      const int* __restrict__ knn_idx,
                                                      const _Float16* __restrict__ W2f,
                                                      const float* __restrict__ b2,
                                                      float* __restrict__ out) {
    __shared__ __align__(16) _Float16 w2s[32768];   // 64 KB: ALL of W2f
    const int t = threadIdx.x, w = t >> 6, lane = t & 63;
    const int quad = lane >> 4, l16 = lane & 15;

    // XCD-aware swizzle: 2048 blocks, XCD x owns logical [256x, 256x+256) = 4 batches.
    const int lb = ((blockIdx.x & 7) << 8) | (blockIdx.x >> 3);

    const int q0 = lb * 16 + w * 2;               // queries q0, q0+1; block covers 16
    const int b = q0 >> 10;
    const int nb0 = knn_idx[q0 * KNN + l16];
    const int nb1 = knn_idx[(q0 + 1) * KNN + l16];
    const _Float16* g0 = Gall + ((size_t)(b << 10) + nb0) * H2;
    const _Float16* g1 = Gall + ((size_t)(b << 10) + nb1) * H2;
    const _Float16* qq0 = Qall + (size_t)q0 * H2;
    const _Float16* qq1 = qq0 + H2;

    // stage entire W2f: 8 x f16x8 per thread
#pragma unroll
    for (int i = 0; i < 8; ++i) {
        f16x8 v = *(const f16x8*)(W2f + (size_t)(i * 4096 + t * 8));
        *(f16x8*)&w2s[i * 4096 + t * 8] = v;
    }

    f32x4 acc[2][8];
#pragma unroll
    for (int tm = 0; tm < 2; ++tm)
#pragma unroll
        for (int nt = 0; nt < 8; ++nt) acc[tm][nt] = (f32x4){0.f, 0.f, 0.f, 0.f};

    __syncthreads();

    // single barrier-free compute region: 8 K-slices of 32
#pragma unroll
    for (int rk = 0; rk < 8; ++rk) {
        const int ho = rk * 32 + quad * 8;
        f16x8 gA = *(const f16x8*)(g0 + ho);
        f16x8 qA = *(const f16x8*)(qq0 + ho);
        f16x8 gB = *(const f16x8*)(g1 + ho);
        f16x8 qB = *(const f16x8*)(qq1 + ho);
        f16x8 a0 = act8(gA, qA);
        f16x8 a1 = act8(gB, qB);
        const _Float16* bb = &w2s[rk * 4096 + lane * 8];
#pragma unroll
        for (int nt = 0; nt < 8; ++nt) {
            f16x8 bf = *(const f16x8*)(bb + nt * 512);
            acc[0][nt] = __builtin_amdgcn_mfma_f32_16x16x32_f16(a0, bf, acc[0][nt], 0, 0, 0);
            acc[1][nt] = __builtin_amdgcn_mfma_f32_16x16x32_f16(a1, bf, acc[1][nt], 0, 0, 0);
        }
    }

    // Epilogue: w2s no longer needed -> alias obuf into it (after a barrier).
    __syncthreads();
    float* obuf = (float*)w2s;       // 8 KB used of 64 KB
#pragma unroll
    for (int tm = 0; tm < 2; ++tm)
#pragma unroll
        for (int nt = 0; nt < 8; ++nt) {
            const float bias = b2[nt * 16 + l16];
            float s = 0.f;
#pragma unroll
            for (int r = 0; r < 4; ++r) s += gelu_poly(acc[tm][nt][r] + bias);
            s += __shfl_xor(s, 16, 64);
            s += __shfl_xor(s, 32, 64);
            if (quad == 0)
                obuf[(w * 2 + tm) * 128 + nt * 16 + l16] = s * 0.0625f;
        }
    __syncthreads();
    {
        // block covers queries [lb*16, lb*16+16) -> 8 KB contiguous in out
        float4 v = *(const float4*)&obuf[t * 4];
        *(float4*)(out + (size_t)lb * 2048 + t * 4) = v;
    }
}

extern "C" void kernel_launch(void* const* d_in, const int* in_sizes, int n_in,
                              void* d_out, int out_size, void* d_ws, size_t ws_size,
                              hipStream_t stream) {
    const float* points   = (const float*)d_in[0];
    const float* features = (const float*)d_in[1];
    const float* W1 = (const float*)d_in[2];
    const float* b1 = (const float*)d_in[3];
    const float* W2 = (const float*)d_in[4];
    const float* b2 = (const float*)d_in[5];
    float* out = (float*)d_out;

    const size_t IDX_B  = (size_t)BB * NN * KNN * 4;   // 2 MB
    const size_t WCF_B  = 512 * 64 * 2;                // 64 KB
    const size_t W2F_B  = 256 * 128 * 2;               // 64 KB
    const size_t G_B    = (size_t)BB * NN * H2 * 2;    // 16 MB

    int* knn_idx = (int*)d_ws;
    char* p = (char*)d_ws + IDX_B;
    _Float16* Wcf  = (_Float16*)p;  p += WCF_B;
    _Float16* W2f  = (_Float16*)p;  p += W2F_B;
    _Float16* Gall = (_Float16*)p;  p += G_B;
    _Float16* Qall = (_Float16*)p;                     // 16 MB -> total ~34.1 MB

    prep_weights<<<16, 512, 0, stream>>>(W1, W2, Wcf, W2f);
    knn_gq<<<5120, 512, 0, stream>>>(points, knn_idx, features, Wcf, b1, Gall, Qall);
    fused_mlp11<<<2048, 512, 0, stream>>>(Gall, Qall, knn_idx, W2f, b2, out);
}

// Round 6
// 188.712 us; speedup vs baseline: 1.0954x; 1.0109x over previous
//
#include <hip/hip_runtime.h>
#include <math.h>

#define BB 32
#define NN 1024
#define FF 64
#define PP 128
#define KNN 16
#define H2 256  // 2P
#define F2 128  // 2F
#define KSEL 17
#define SVCAP 272

typedef float f32x4 __attribute__((ext_vector_type(4)));
typedef _Float16 f16x8 __attribute__((ext_vector_type(8)));
typedef _Float16 f16x4 __attribute__((ext_vector_type(4)));
typedef _Float16 f16x2 __attribute__((ext_vector_type(2)));

// ---- transcendental-free gelu: y = x * (0.5 + xc*P(xc^2)), xc = clamp(x, +-3.3)
#define GC1 0.39616247f
#define GC3 -0.05891477f
#define GC5 0.00563735f
#define GC7 -2.10439e-4f
#define GXC 3.2988f

__device__ __forceinline__ f16x8 splat8(float f) {
    _Float16 h = (_Float16)f;
    f16x8 v = {h, h, h, h, h, h, h, h};
    return v;
}
__device__ __forceinline__ f16x4 splat4(float f) {
    _Float16 h = (_Float16)f;
    f16x4 v = {h, h, h, h};
    return v;
}

// packed-f16 activation for 8 elements: gelu(g + q); v_pk_{add,mul,fma,min,max}_f16
__device__ __forceinline__ f16x8 act8(f16x8 gv, f16x8 qv) {
    const f16x8 XL = splat8(-GXC), XH = splat8(GXC);
    const f16x8 C1 = splat8(GC1), C3 = splat8(GC3), C5 = splat8(GC5), C7 = splat8(GC7);
    const f16x8 HF = splat8(0.5f);
    f16x8 x  = gv + qv;
    f16x8 xc = __builtin_elementwise_min(__builtin_elementwise_max(x, XL), XH);
    f16x8 s  = xc * xc;
    f16x8 t  = s * C7 + C5;
    t = s * t + C3;
    t = s * t + C1;
    f16x8 u = xc * t + HF;
    return x * u;
}

// packed-f16 epilogue: sum_r gelu(acc[r] + bias) over the 4 in-lane k-rows
__device__ __forceinline__ float gelu4_sum(f32x4 a, float bias) {
    f16x4 x;
    x[0] = (_Float16)(a[0] + bias);
    x[1] = (_Float16)(a[1] + bias);
    x[2] = (_Float16)(a[2] + bias);
    x[3] = (_Float16)(a[3] + bias);
    const f16x4 XL = splat4(-GXC), XH = splat4(GXC);
    const f16x4 C1 = splat4(GC1), C3 = splat4(GC3), C5 = splat4(GC5), C7 = splat4(GC7);
    const f16x4 HF = splat4(0.5f);
    f16x4 xc = __builtin_elementwise_min(__builtin_elementwise_max(x, XL), XH);
    f16x4 s  = xc * xc;
    f16x4 t  = s * C7 + C5;
    t = s * t + C3;
    t = s * t + C1;
    f16x4 u = xc * t + HF;
    f16x4 y = x * u;
    f16x2 y2 = __builtin_shufflevector(y, y, 0, 1) + __builtin_shufflevector(y, y, 2, 3);
    return (float)y2[0] + (float)y2[1];
}

// ------- prep_weights: fragment-swizzled Wcf (gq B-operand) + W2f (fused B) --------
__global__ __launch_bounds__(512) void prep_weights(const float* __restrict__ W1,
                                                    const float* __restrict__ W2,
                                                    _Float16* __restrict__ Wcf,
                                                    _Float16* __restrict__ W2f) {
    int tid = blockIdx.x * 512 + threadIdx.x;   // 0..8191
    if (tid < 4096) {
        const int lane = tid & 63, quad = lane >> 4, l16 = lane & 15;
        const int kk = (tid >> 6) & 1, n_tile = tid >> 7;
        const int n = n_tile * 16 + l16;
        const int kb = kk * 32 + quad * 8;
        f16x8 v;
#pragma unroll
        for (int j = 0; j < 8; ++j) {
            const int k = kb + j;
            float x = (n < 256) ? W1[k * 256 + n]
                                : (W1[(64 + k) * 256 + (n - 256)] - W1[k * 256 + (n - 256)]);
            v[j] = (_Float16)x;
        }
        *(f16x8*)(Wcf + (size_t)tid * 8) = v;
    } else {
        const int t2 = tid - 4096;
        const int lane = t2 & 63, quad = lane >> 4, l16 = lane & 15;
        const int nt = (t2 >> 6) & 7, kk8 = t2 >> 9;
        const int p = nt * 16 + l16;
        const int hb = kk8 * 32 + quad * 8;
        f16x8 v;
#pragma unroll
        for (int j = 0; j < 8; ++j) v[j] = (_Float16)W2[(size_t)(hb + j) * PP + p];
        *(f16x8*)(W2f + (size_t)t2 * 8) = v;
    }
}

// ------- knn_gq: blocks 0..4095 = set-based kNN; 4096..5119 = G/Q GEMM -------------
__global__ __launch_bounds__(512, 8) void knn_gq(const float* __restrict__ points,
                                                 int* __restrict__ idx_out,
                                                 const float* __restrict__ feat,
                                                 const _Float16* __restrict__ Wcf,
                                                 const float* __restrict__ b1,
                                                 _Float16* __restrict__ Gall,
                                                 _Float16* __restrict__ Qall) {
    // one LDS arena, aliased per path (kNN: 35840 B, gq: 34816 B)
    __shared__ __align__(16) unsigned char smem[35840];
    const int t = threadIdx.x;

    if (blockIdx.x >= 4096) {
        // ---------------- gq path: 32 rows/block, 8 waves (two 16-row subtiles) ----
        _Float16 (*st)[16][136] = (_Float16(*)[16][136])smem;
        const int w8 = t >> 6, lane = t & 63;
        const int w4 = w8 & 3;                       // role within subtile
        const int quad = lane >> 4, l16 = lane & 15;
        const int gb = blockIdx.x - 4096;            // 0..1023
        const int m0 = gb * 32 + (w8 >> 2) * 16;

        f16x8 a[2];
#pragma unroll
        for (int kk = 0; kk < 2; ++kk) {
            const float* ap = feat + (size_t)(m0 + l16) * 64 + kk * 32 + quad * 8;
            float4 a0 = *(const float4*)ap, a1 = *(const float4*)(ap + 4);
            f16x8 v;
            v[0] = (_Float16)a0.x; v[1] = (_Float16)a0.y; v[2] = (_Float16)a0.z; v[3] = (_Float16)a0.w;
            v[4] = (_Float16)a1.x; v[5] = (_Float16)a1.y; v[6] = (_Float16)a1.z; v[7] = (_Float16)a1.w;
            a[kk] = v;
        }
        f32x4 acc[8];
#pragma unroll
        for (int nt = 0; nt < 8; ++nt) acc[nt] = (f32x4){0.f, 0.f, 0.f, 0.f};
#pragma unroll
        for (int kk = 0; kk < 2; ++kk)
#pragma unroll
            for (int nt = 0; nt < 8; ++nt) {
                f16x8 bf = *(const f16x8*)(Wcf + (size_t)(((w4 * 8 + nt) * 2 + kk) * 64 + lane) * 8);
                acc[nt] = __builtin_amdgcn_mfma_f32_16x16x32_f16(a[kk], bf, acc[nt], 0, 0, 0);
            }

        const bool isQ = (w4 >= 2);
#pragma unroll
        for (int nt = 0; nt < 8; ++nt) {
            const int col = nt * 16 + l16;
            const float bias = isQ ? b1[(w4 - 2) * 128 + col] : 0.f;
#pragma unroll
            for (int r = 0; r < 4; ++r)
                st[w8][quad * 4 + r][col] = (_Float16)(acc[nt][r] + bias);
        }
        __syncthreads();

        const int row = lane >> 2, c = lane & 3;
        const int m = m0 + row;
#pragma unroll
        for (int i = 0; i < 4; ++i) {
            const int col = c * 32 + i * 8;
            f16x8 v = *(const f16x8*)&st[w8][row][col];
            if (!isQ) *(f16x8*)(Gall + (size_t)m * H2 + w4 * 128 + col) = v;
            else      *(f16x8*)(Qall + (size_t)m * H2 + (w4 - 2) * 128 + col) = v;
        }
        return;
    }

    // ---------------- kNN path ----------------
    // points packed as float2 pairs: 2x ds_read_b64 per distance (was 4x b32);
    // 8 B lane stride = 2-way bank aliasing = free. Same values, same arithmetic,
    // so the selection (and tie behavior) is bit-identical to the previous version.
    float2* pxy = (float2*)smem;                                // 8 KB
    float2* pzr = (float2*)(smem + 8192);                       // 8 KB
    unsigned (*sv_val)[SVCAP] = (unsigned(*)[SVCAP])(smem + 16384);   // 8704 B
    unsigned (*sv_idx)[SVCAP] = (unsigned(*)[SVCAP])(smem + 25088);   // 8704 B
    unsigned (*tie_idx)[64]   = (unsigned(*)[64])(smem + 33792);      // 2048 B

    const int w = t >> 6, lane = t & 63;
    const int b = blockIdx.x >> 7;
    const int q0 = (blockIdx.x & 127) * 8;
    const float* pb = points + (size_t)b * NN * 3;
    const unsigned long long lt = (1ull << lane) - 1ull;

    for (int i = t; i < NN; i += 512) {
        float x = pb[3 * i], y = pb[3 * i + 1], z = pb[3 * i + 2];
        float r = __fadd_rn(__fadd_rn(__fmul_rn(x, x), __fmul_rn(y, y)), __fmul_rn(z, z));
        pxy[i] = make_float2(x, y);
        pzr[i] = make_float2(z, r);
    }
    __syncthreads();

    const int qn = q0 + w;
    const int gq = b * NN + qn;
    const float2 qv1 = pxy[qn], qv2 = pzr[qn];
    const float qx = qv1.x, qy = qv1.y, qz = qv2.x, qw = qv2.y;

    float D[16];
#pragma unroll
    for (int j = 0; j < 16; ++j) {
        const int m = j * 64 + lane;
        const float2 v1 = pxy[m], v2 = pzr[m];
        float dot = __fadd_rn(__fadd_rn(__fmul_rn(qx, v1.x), __fmul_rn(qy, v1.y)),
                              __fmul_rn(qz, v2.x));
        D[j] = __fadd_rn(__fadd_rn(__fsub_rn(qw, __fmul_rn(2.0f, dot)), v2.y), 1e-5f);
    }

    float mnf = D[0];
#pragma unroll
    for (int j = 1; j < 16; ++j) mnf = fminf(mnf, D[j]);
    const unsigned mbits = __float_as_uint(mnf);

    // T_ub via 16-round radix on the HIGH 16 bits of the lane-mins.
    const unsigned mhi = mbits >> 16;
    unsigned Thi = 0;
#pragma unroll
    for (int bit = 15; bit >= 0; --bit) {
        unsigned cand = Thi | (1u << bit);
        int cnt = __popcll(__ballot(mhi < cand));
        if (cnt < KSEL) Thi = cand;
    }
    const unsigned T = (Thi << 16) | 0xFFFFu;

    unsigned base = 0;
#pragma unroll
    for (int j = 0; j < 16; ++j) {
        unsigned vb = __float_as_uint(D[j]);
        bool keep = (vb <= T);
        unsigned long long m = __ballot(keep);
        if (keep) {
            unsigned pos = base + (unsigned)__popcll(m & lt);
            if (pos < SVCAP) { sv_val[w][pos] = vb; sv_idx[w][pos] = j * 64 + lane; }
        }
        base += (unsigned)__popcll(m);
    }
    unsigned C = base > SVCAP ? SVCAP : base;
    const int S = (int)((C + 63) >> 6);

    unsigned Ts = 0;
    if (S == 1) {
        unsigned xv0 = (lane < (int)C) ? sv_val[w][lane] : 0xFFFFFFFFu;
#pragma unroll
        for (int bit = 31; bit >= 0; --bit) {
            unsigned cand = Ts | (1u << bit);
            int cnt = __popcll(__ballot(xv0 < cand));
            if (cnt < KSEL) Ts = cand;
        }
    } else {
        for (int bit = 31; bit >= 0; --bit) {
            unsigned cand = Ts | (1u << bit);
            int cnt = 0;
            for (int s = 0; s < S; ++s) {
                int i = s * 64 + lane;
                unsigned vb = (i < (int)C) ? sv_val[w][i] : 0xFFFFFFFFu;
                cnt += __popcll(__ballot(vb < cand));
            }
            if (cnt < KSEL) Ts = cand;
        }
    }

    int L = 0;
    for (int s = 0; s < S; ++s) {
        int i = s * 64 + lane;
        unsigned vb = (i < (int)C) ? sv_val[w][i] : 0xFFFFFFFFu;
        L += __popcll(__ballot(vb < Ts));
    }
    const int need = KSEL - L;

    unsigned vmin_l = 0xFFFFFFFFu;
    for (int s = 0; s < S; ++s) {
        int i = s * 64 + lane;
        unsigned vb = (i < (int)C) ? sv_val[w][i] : 0xFFFFFFFFu;
        vmin_l = vmin_l < vb ? vmin_l : vb;
    }
#pragma unroll
    for (int off = 32; off >= 1; off >>= 1) {
        unsigned o2 = __shfl_xor(vmin_l, off, 64);
        vmin_l = vmin_l < o2 ? vmin_l : o2;
    }
    const unsigned Vmin = vmin_l;
    unsigned imin_l = 0xFFFFFFFFu;
    for (int s = 0; s < S; ++s) {
        int i = s * 64 + lane;
        unsigned vb = (i < (int)C) ? sv_val[w][i] : 0xFFFFFFFFu;
        unsigned mi = (i < (int)C) ? sv_idx[w][i] : 0xFFFFFFFFu;
        if (vb == Vmin && mi < imin_l) imin_l = mi;
    }
#pragma unroll
    for (int off = 32; off >= 1; off >>= 1) {
        unsigned o2 = __shfl_xor(imin_l, off, 64);
        imin_l = imin_l < o2 ? imin_l : o2;
    }
    const unsigned dropIdx = imin_l;

    int* o = idx_out + (size_t)gq * KNN;
    unsigned wbase = 0, tbase = 0;
    for (int s = 0; s < S; ++s) {
        int i = s * 64 + lane;
        unsigned vb = (i < (int)C) ? sv_val[w][i] : 0xFFFFFFFFu;
        unsigned mi = (i < (int)C) ? sv_idx[w][i] : 0xFFFFFFFFu;
        bool wk = (vb < Ts) && (mi != dropIdx);
        unsigned long long wm = __ballot(wk);
        if (wk) o[wbase + (unsigned)__popcll(wm & lt)] = (int)mi;
        wbase += (unsigned)__popcll(wm);
        bool tk = (vb == Ts);
        unsigned long long tm2 = __ballot(tk);
        if (tk) {
            unsigned tp = tbase + (unsigned)__popcll(tm2 & lt);
            if (tp < 64) tie_idx[w][tp] = mi;
        }
        tbase += (unsigned)__popcll(tm2);
    }
    unsigned tc = tbase > 64 ? 64 : tbase;
    if ((int)tc == need) {
        bool tk = (lane < (int)tc);
        unsigned mi2 = tk ? tie_idx[w][lane] : 0xFFFFFFFFu;
        tk = tk && (mi2 != dropIdx);
        unsigned long long m3 = __ballot(tk);
        if (tk) o[wbase + (unsigned)__popcll(m3 & lt)] = (int)mi2;
    } else if (lane == 0) {
        unsigned pos = wbase;
        for (int r = 0; r < need; ++r) {
            unsigned best = 0xFFFFFFFFu; int bj = 0;
            for (int j2 = 0; j2 < (int)tc; ++j2) {
                unsigned mi = tie_idx[w][j2];
                if (mi < best) { best = mi; bj = j2; }
            }
            tie_idx[w][bj] = 0xFFFFFFFFu;
            if (best != dropIdx) o[pos++] = (int)best;
        }
    }
}

// ---------------- fused_mlp12: out = mean_k gelu(gelu(G[idx]+Q) @ W2 + b2) ----------
// Round-5 post-mortem: VGPR pinned at 64 by launch_bounds(512,4) (acc eats 64 AGPR
// of the 128-reg cap) -> no register room to pipeline the 32 independent L2-gather
// loads; measured occupancy (~12 waves/CU) is already at the 3-waves/SIMD level.
// This version trades the 16-wave cap for ILP: launch_bounds(512,3) frees ~40 VGPRs
// for the scheduler to hoist 2-3 rk-steps of gathers. Epilogue gelu now packed f16.
__global__ __launch_bounds__(512, 3) void fused_mlp12(const _Float16* __restrict__ Gall,
                                                      const _Float16* __restrict__ Qall,
                                                      const int* __restrict__ knn_idx,
                                                      const _Float16* __restrict__ W2f,
                                                      const float* __restrict__ b2,
                                                      float* __restrict__ out) {
    __shared__ __align__(16) _Float16 w2s[32768];   // 64 KB: ALL of W2f
    const int t = threadIdx.x, w = t >> 6, lane = t & 63;
    const int quad = lane >> 4, l16 = lane & 15;

    // XCD-aware swizzle: 2048 blocks, XCD x owns logical [256x, 256x+256) = 4 batches.
    const int lb = ((blockIdx.x & 7) << 8) | (blockIdx.x >> 3);

    const int q0 = lb * 16 + w * 2;               // queries q0, q0+1; block covers 16
    const int b = q0 >> 10;
    const int nb0 = knn_idx[q0 * KNN + l16];
    const int nb1 = knn_idx[(q0 + 1) * KNN + l16];
    const _Float16* g0 = Gall + ((size_t)(b << 10) + nb0) * H2;
    const _Float16* g1 = Gall + ((size_t)(b << 10) + nb1) * H2;
    const _Float16* qq0 = Qall + (size_t)q0 * H2;
    const _Float16* qq1 = qq0 + H2;

    // stage entire W2f: 8 x f16x8 per thread
#pragma unroll
    for (int i = 0; i < 8; ++i) {
        f16x8 v = *(const f16x8*)(W2f + (size_t)(i * 4096 + t * 8));
        *(f16x8*)&w2s[i * 4096 + t * 8] = v;
    }

    f32x4 acc[2][8];
#pragma unroll
    for (int tm = 0; tm < 2; ++tm)
#pragma unroll
        for (int nt = 0; nt < 8; ++nt) acc[tm][nt] = (f32x4){0.f, 0.f, 0.f, 0.f};

    __syncthreads();

    // single barrier-free compute region: 8 K-slices of 32
#pragma unroll
    for (int rk = 0; rk < 8; ++rk) {
        const int ho = rk * 32 + quad * 8;
        f16x8 gA = *(const f16x8*)(g0 + ho);
        f16x8 qA = *(const f16x8*)(qq0 + ho);
        f16x8 gB = *(const f16x8*)(g1 + ho);
        f16x8 qB = *(const f16x8*)(qq1 + ho);
        f16x8 a0 = act8(gA, qA);
        f16x8 a1 = act8(gB, qB);
        const _Float16* bb = &w2s[rk * 4096 + lane * 8];
#pragma unroll
        for (int nt = 0; nt < 8; ++nt) {
            f16x8 bf = *(const f16x8*)(bb + nt * 512);
            acc[0][nt] = __builtin_amdgcn_mfma_f32_16x16x32_f16(a0, bf, acc[0][nt], 0, 0, 0);
            acc[1][nt] = __builtin_amdgcn_mfma_f32_16x16x32_f16(a1, bf, acc[1][nt], 0, 0, 0);
        }
    }

    // Epilogue: w2s no longer needed -> alias obuf into it (after a barrier).
    __syncthreads();
    float* obuf = (float*)w2s;       // 8 KB used of 64 KB
#pragma unroll
    for (int tm = 0; tm < 2; ++tm)
#pragma unroll
        for (int nt = 0; nt < 8; ++nt) {
            const float bias = b2[nt * 16 + l16];
            float s = gelu4_sum(acc[tm][nt], bias);
            s += __shfl_xor(s, 16, 64);
            s += __shfl_xor(s, 32, 64);
            if (quad == 0)
                obuf[(w * 2 + tm) * 128 + nt * 16 + l16] = s * 0.0625f;
        }
    __syncthreads();
    {
        // block covers queries [lb*16, lb*16+16) -> 8 KB contiguous in out
        float4 v = *(const float4*)&obuf[t * 4];
        *(float4*)(out + (size_t)lb * 2048 + t * 4) = v;
    }
}

extern "C" void kernel_launch(void* const* d_in, const int* in_sizes, int n_in,
                              void* d_out, int out_size, void* d_ws, size_t ws_size,
                              hipStream_t stream) {
    const float* points   = (const float*)d_in[0];
    const float* features = (const float*)d_in[1];
    const float* W1 = (const float*)d_in[2];
    const float* b1 = (const float*)d_in[3];
    const float* W2 = (const float*)d_in[4];
    const float* b2 = (const float*)d_in[5];
    float* out = (float*)d_out;

    const size_t IDX_B  = (size_t)BB * NN * KNN * 4;   // 2 MB
    const size_t WCF_B  = 512 * 64 * 2;                // 64 KB
    const size_t W2F_B  = 256 * 128 * 2;               // 64 KB
    const size_t G_B    = (size_t)BB * NN * H2 * 2;    // 16 MB

    int* knn_idx = (int*)d_ws;
    char* p = (char*)d_ws + IDX_B;
    _Float16* Wcf  = (_Float16*)p;  p += WCF_B;
    _Float16* W2f  = (_Float16*)p;  p += W2F_B;
    _Float16* Gall = (_Float16*)p;  p += G_B;
    _Float16* Qall = (_Float16*)p;                     // 16 MB -> total ~34.1 MB

    prep_weights<<<16, 512, 0, stream>>>(W1, W2, Wcf, W2f);
    knn_gq<<<5120, 512, 0, stream>>>(points, knn_idx, features, Wcf, b1, Gall, Qall);
    fused_mlp12<<<2048, 512, 0, stream>>>(Gall, Qall, knn_idx, W2f, b2, out);
}